// Round 1
// baseline (6916.949 us; speedup 1.0000x reference)
//
#include <hip/hip_runtime.h>
#include <stdint.h>

typedef unsigned short ushort_t;

#define HD 1024
#define G4 4096
#define NB 4
#define TT 128
#define UU 64
#define NFEAT 80
#define SMAXD 4096
#define JD 640
#define NV 64

static __device__ __forceinline__ float lo2f(uint32_t u) {
  union { uint32_t i; float f; } v; v.i = u << 16; return v.f;
}
static __device__ __forceinline__ float hi2f(uint32_t u) {
  union { uint32_t i; float f; } v; v.i = u & 0xffff0000u; return v.f;
}
static __device__ __forceinline__ ushort_t f2bf(float f) {
  union { uint32_t i; float f; } v; v.f = f;
  return (ushort_t)((v.i + 0x7fffu + ((v.i >> 16) & 1u)) >> 16);
}

// ---------------- transpose: src [K,N] f32 -> dst [N,K] ----------------
__global__ void transpose_f32(const float* __restrict__ src, float* __restrict__ dst,
                              int K, int N) {
  __shared__ float tile[32][33];
  int n0 = blockIdx.x * 32, k0 = blockIdx.y * 32;
  int tx = threadIdx.x, ty = threadIdx.y;
#pragma unroll
  for (int j = 0; j < 32; j += 8)
    tile[ty + j][tx] = src[(size_t)(k0 + ty + j) * N + n0 + tx];
  __syncthreads();
#pragma unroll
  for (int j = 0; j < 32; j += 8)
    dst[(size_t)(n0 + ty + j) * K + k0 + tx] = tile[tx][ty + j];
}

__global__ void transpose_bf16(const float* __restrict__ src, ushort_t* __restrict__ dst,
                               int K, int N) {
  __shared__ float tile[32][33];
  int n0 = blockIdx.x * 32, k0 = blockIdx.y * 32;
  int tx = threadIdx.x, ty = threadIdx.y;
#pragma unroll
  for (int j = 0; j < 32; j += 8)
    tile[ty + j][tx] = src[(size_t)(k0 + ty + j) * N + n0 + tx];
  __syncthreads();
#pragma unroll
  for (int j = 0; j < 32; j += 8)
    dst[(size_t)(n0 + ty + j) * K + k0 + tx] = f2bf(tile[tx][ty + j]);
}

// -------- input projection: C[m,:] = X[m,:K] @ W[K,4096] + bias (one block per row m)
__global__ __launch_bounds__(256) void inproj_kernel(
    const float* __restrict__ X, const float* __restrict__ W,
    const float* __restrict__ bias, float* __restrict__ C, int K) {
  __shared__ float xls[JD];
  int m = blockIdx.x;
  int tid = threadIdx.x;
  for (int i = tid; i < K; i += 256) xls[i] = X[(size_t)m * K + i];
  __syncthreads();
  for (int c = tid; c < G4; c += 256) {
    float acc = bias[c];
    for (int k = 0; k < K; ++k) acc = fmaf(xls[k], W[(size_t)k * G4 + c], acc);
    C[(size_t)m * G4 + c] = acc;
  }
}

// -------- cs[c] = bs[c] + sum_k bj[k] * Ws[k,c] ; grid 16 x 256
__global__ __launch_bounds__(256) void cs_kernel(const float* __restrict__ bj,
                                                 const float* __restrict__ Ws,
                                                 const float* __restrict__ bs,
                                                 float* __restrict__ cs) {
  __shared__ float bl[JD];
  int tid = threadIdx.x;
  for (int i = tid; i < JD; i += 256) bl[i] = bj[i];
  __syncthreads();
  int c = blockIdx.x * 256 + tid;
  float acc = bs[c];
  for (int k = 0; k < JD; ++k) acc = fmaf(bl[k], Ws[(size_t)k * G4 + c], acc);
  cs[c] = acc;
}

// -------- generic GEMM: C[M,N] = A[M,K] @ B[K,N] (+ bias over N). 64x64 tile, BK=32.
__global__ __launch_bounds__(256) void gemm_kernel(
    const float* __restrict__ A, const float* __restrict__ Bm,
    const float* __restrict__ bias, float* __restrict__ C,
    int M, int N, int K) {
  __shared__ float As[32][68];
  __shared__ float Bs[32][68];
  int n0 = blockIdx.x * 64, m0 = blockIdx.y * 64;
  int tid = threadIdx.x;
  int tx = tid & 15, ty = tid >> 4;
  float acc[4][4] = {};
  for (int k0 = 0; k0 < K; k0 += 32) {
#pragma unroll
    for (int i = 0; i < 8; ++i) {
      int idx = tid + i * 256;
      int ml = idx >> 5, kl = idx & 31;
      As[kl][ml] = A[(size_t)(m0 + ml) * K + k0 + kl];
      int kl2 = idx >> 6, nl = idx & 63;
      Bs[kl2][nl] = Bm[(size_t)(k0 + kl2) * N + n0 + nl];
    }
    __syncthreads();
#pragma unroll 8
    for (int k = 0; k < 32; ++k) {
      float4 a4 = *(const float4*)&As[k][ty * 4];
      float4 b4 = *(const float4*)&Bs[k][tx * 4];
      acc[0][0] = fmaf(a4.x, b4.x, acc[0][0]);
      acc[0][1] = fmaf(a4.x, b4.y, acc[0][1]);
      acc[0][2] = fmaf(a4.x, b4.z, acc[0][2]);
      acc[0][3] = fmaf(a4.x, b4.w, acc[0][3]);
      acc[1][0] = fmaf(a4.y, b4.x, acc[1][0]);
      acc[1][1] = fmaf(a4.y, b4.y, acc[1][1]);
      acc[1][2] = fmaf(a4.y, b4.z, acc[1][2]);
      acc[1][3] = fmaf(a4.y, b4.w, acc[1][3]);
      acc[2][0] = fmaf(a4.z, b4.x, acc[2][0]);
      acc[2][1] = fmaf(a4.z, b4.y, acc[2][1]);
      acc[2][2] = fmaf(a4.z, b4.z, acc[2][2]);
      acc[2][3] = fmaf(a4.z, b4.w, acc[2][3]);
      acc[3][0] = fmaf(a4.w, b4.x, acc[3][0]);
      acc[3][1] = fmaf(a4.w, b4.y, acc[3][1]);
      acc[3][2] = fmaf(a4.w, b4.z, acc[3][2]);
      acc[3][3] = fmaf(a4.w, b4.w, acc[3][3]);
    }
    __syncthreads();
  }
  float b0 = 0.f, b1 = 0.f, b2 = 0.f, b3 = 0.f;
  if (bias) {
    b0 = bias[n0 + tx * 4 + 0]; b1 = bias[n0 + tx * 4 + 1];
    b2 = bias[n0 + tx * 4 + 2]; b3 = bias[n0 + tx * 4 + 3];
  }
#pragma unroll
  for (int i = 0; i < 4; ++i) {
    float4 o;
    o.x = acc[i][0] + b0; o.y = acc[i][1] + b1; o.z = acc[i][2] + b2; o.w = acc[i][3] + b3;
    *(float4*)&C[(size_t)(m0 + ty * 4 + i) * N + n0 + tx * 4] = o;
  }
}

// -------- persistent dual-layer LSTM stepper, 256 blocks x 256 threads.
// blocks [0,128): layer A (encoder, fp32 Ut); blocks [128,256): layer B (pred, bf16 Ut).
// Each block owns 8 hidden indices; one global barrier per timestep.
__global__ __launch_bounds__(256) void lstm_kernel(
    const float* __restrict__ xgA, int lenA,
    const float* __restrict__ UtA,     // [4096][1024] f32 (transposed)
    const float* __restrict__ cinitA,  // [4*1024] or nullptr
    float* __restrict__ hseqA,         // [4, lenA, 1024]
    float* __restrict__ hbufA,         // [2][4*1024]
    float* __restrict__ finalA,        // nullptr or [2][4][1024] (h then c)
    const float* __restrict__ xgB, int lenB,  // table [64,4096] if tokB else [4,lenB,4096]
    const int* __restrict__ tokB,
    const ushort_t* __restrict__ UtB,  // [4096][1024] bf16 (transposed)
    float* __restrict__ hseqB,
    float* __restrict__ hbufB,
    unsigned int* __restrict__ bar) {
  __shared__ float hprev[NB][HD];     // 16KB
  __shared__ float red[8][NB][32];    // 4KB
  __shared__ float gl[NB][32];
  __shared__ float cst[NB][8];
  int blk = blockIdx.x;
  int isA = (blk < 128) ? 1 : 0;
  int p = blk & 127;
  int tid = threadIdx.x;
  int c = tid & 31, s = tid >> 5;     // col-local, k-slice
  int len = isA ? lenA : lenB;
  const float* xg = isA ? xgA : xgB;
  float* hseq = isA ? hseqA : hseqB;
  float* hbuf = isA ? hbufA : hbufB;

  if (tid < 32) {
    int bb = tid >> 3, hh = tid & 7;
    cst[bb][hh] = (isA && cinitA) ? cinitA[bb * HD + p * 8 + hh] : 0.0f;
  }

  int gate = c >> 3, hic = c & 7;
  int ucol = gate * HD + p * 8 + hic;
  int kb = s * 128;
  float* hp = &hprev[0][0];

  int steps = lenA;  // lenA >= lenB
  for (int t = 0; t < steps; ++t) {
    int par = t & 1;
    int active = (t < len) ? 1 : 0;
    const float* hsrc = hbuf + par * (NB * HD);
    if (active) {
      for (int i = tid; i < NB * HD; i += 256) hp[i] = hsrc[i];
    }
    __syncthreads();
    if (active) {
      float aa[4] = {0.f, 0.f, 0.f, 0.f};
      if (isA) {
        const float* ur = UtA + (size_t)ucol * HD + kb;
#pragma unroll 4
        for (int k = 0; k < 128; k += 4) {
          float4 u4 = *(const float4*)(ur + k);
#pragma unroll
          for (int bb = 0; bb < 4; ++bb) {
            float4 h4 = *(const float4*)&hprev[bb][kb + k];
            aa[bb] = fmaf(u4.x, h4.x, aa[bb]);
            aa[bb] = fmaf(u4.y, h4.y, aa[bb]);
            aa[bb] = fmaf(u4.z, h4.z, aa[bb]);
            aa[bb] = fmaf(u4.w, h4.w, aa[bb]);
          }
        }
      } else {
        const ushort_t* ur = UtB + (size_t)ucol * HD + kb;
#pragma unroll 2
        for (int k = 0; k < 128; k += 8) {
          uint4 uu = *(const uint4*)(ur + k);
          float u0 = lo2f(uu.x), u1 = hi2f(uu.x), u2 = lo2f(uu.y), u3 = hi2f(uu.y);
          float u4v = lo2f(uu.z), u5 = hi2f(uu.z), u6 = lo2f(uu.w), u7 = hi2f(uu.w);
#pragma unroll
          for (int bb = 0; bb < 4; ++bb) {
            float4 hA = *(const float4*)&hprev[bb][kb + k];
            float4 hB = *(const float4*)&hprev[bb][kb + k + 4];
            float t0 = fmaf(u0, hA.x, fmaf(u1, hA.y, fmaf(u2, hA.z, u3 * hA.w)));
            float t1 = fmaf(u4v, hB.x, fmaf(u5, hB.y, fmaf(u6, hB.z, u7 * hB.w)));
            aa[bb] += t0 + t1;
          }
        }
      }
      red[s][0][c] = aa[0]; red[s][1][c] = aa[1];
      red[s][2][c] = aa[2]; red[s][3][c] = aa[3];
    }
    __syncthreads();
    if (active && tid < 128) {
      int bb = tid >> 5, cc = tid & 31;
      float g = red[0][bb][cc] + red[1][bb][cc] + red[2][bb][cc] + red[3][bb][cc] +
                red[4][bb][cc] + red[5][bb][cc] + red[6][bb][cc] + red[7][bb][cc];
      int gg = cc >> 3, hh = cc & 7;
      int uc = gg * HD + p * 8 + hh;
      float xv;
      if (!isA && tokB) {
        int token = tokB[bb * lenB + t];
        xv = xg[(size_t)token * G4 + uc];
      } else {
        xv = xg[((size_t)bb * len + t) * G4 + uc];
      }
      gl[bb][cc] = g + xv;
    }
    __syncthreads();
    if (active && tid < 32) {
      int bb = tid >> 3, hh = tid & 7;
      float gi = gl[bb][hh], gf = gl[bb][8 + hh], gc = gl[bb][16 + hh], go = gl[bb][24 + hh];
      float si = 1.0f / (1.0f + expf(-gi));
      float sf = 1.0f / (1.0f + expf(-gf));
      float so = 1.0f / (1.0f + expf(-go));
      float cN = sf * cst[bb][hh] + si * tanhf(gc);
      float hN = so * tanhf(cN);
      cst[bb][hh] = cN;
      int hidx = p * 8 + hh;
      hbuf[(par ^ 1) * (NB * HD) + bb * HD + hidx] = hN;
      hseq[((size_t)bb * len + t) * HD + hidx] = hN;
      if (isA && finalA && t == len - 1) {
        finalA[bb * HD + hidx] = hN;
        finalA[NB * HD + bb * HD + hidx] = cN;
      }
      __threadfence();
    }
    __syncthreads();
    if (t + 1 < steps) {
      if (tid == 0) {
        atomicAdd(bar, 1u);
        unsigned int target = 256u * (unsigned int)(t + 1);
        while (__hip_atomic_load(bar, __ATOMIC_RELAXED, __HIP_MEMORY_SCOPE_AGENT) < target) {
          __builtin_amdgcn_s_sleep(2);
        }
        __threadfence();
      }
      __syncthreads();
    }
  }
}

// -------- fused softmax + s@Wp + bp. One block per (b,t); 64u x 64v output tile.
__global__ __launch_bounds__(256) void final_kernel(
    const float* __restrict__ xsA, const float* __restrict__ psA,
    const float* __restrict__ csA, const float* __restrict__ Wp,
    const float* __restrict__ bp, float* __restrict__ out) {
  __shared__ float xc[SMAXD];       // 16KB
  __shared__ float el[64][68];      // 17.4KB  e[k][u]
  __shared__ float wl[64][68];      // 17.4KB  Wp[k][v]
  __shared__ float Dl[64];
  int bt = blockIdx.x;
  int b = bt >> 7, t = bt & 127;
  int tid = threadIdx.x;
  int tx = tid & 15, uy = tid >> 4;
  for (int i = tid; i < SMAXD; i += 256) xc[i] = xsA[(size_t)bt * SMAXD + i] + csA[i];
  const float* psrow = psA + (size_t)b * UU * SMAXD;
  float acc[4][4] = {};
  float d0 = 0.f, d1 = 0.f, d2 = 0.f, d3 = 0.f;
  for (int k0 = 0; k0 < SMAXD; k0 += 64) {
    __syncthreads();
#pragma unroll
    for (int i = 0; i < 16; ++i) {
      int idx = tid + i * 256;
      int kl = idx >> 6, vl = idx & 63;
      wl[kl][vl] = Wp[(size_t)(k0 + kl) * NV + vl];
    }
#pragma unroll
    for (int i = 0; i < 16; ++i) {
      int idx = tid + i * 256;
      int u = idx >> 6, kl = idx & 63;
      float l = xc[k0 + kl] + psrow[(size_t)u * SMAXD + k0 + kl];
      el[kl][u] = __expf(l);   // logits are tiny; shared-shift softmax needs no max pass
    }
    __syncthreads();
#pragma unroll 4
    for (int k = 0; k < 64; ++k) {
      float4 e4 = *(const float4*)&el[k][uy * 4];
      float4 w4 = *(const float4*)&wl[k][tx * 4];
      d0 += e4.x; d1 += e4.y; d2 += e4.z; d3 += e4.w;
      acc[0][0] = fmaf(e4.x, w4.x, acc[0][0]);
      acc[0][1] = fmaf(e4.x, w4.y, acc[0][1]);
      acc[0][2] = fmaf(e4.x, w4.z, acc[0][2]);
      acc[0][3] = fmaf(e4.x, w4.w, acc[0][3]);
      acc[1][0] = fmaf(e4.y, w4.x, acc[1][0]);
      acc[1][1] = fmaf(e4.y, w4.y, acc[1][1]);
      acc[1][2] = fmaf(e4.y, w4.z, acc[1][2]);
      acc[1][3] = fmaf(e4.y, w4.w, acc[1][3]);
      acc[2][0] = fmaf(e4.z, w4.x, acc[2][0]);
      acc[2][1] = fmaf(e4.z, w4.y, acc[2][1]);
      acc[2][2] = fmaf(e4.z, w4.z, acc[2][2]);
      acc[2][3] = fmaf(e4.z, w4.w, acc[2][3]);
      acc[3][0] = fmaf(e4.w, w4.x, acc[3][0]);
      acc[3][1] = fmaf(e4.w, w4.y, acc[3][1]);
      acc[3][2] = fmaf(e4.w, w4.z, acc[3][2]);
      acc[3][3] = fmaf(e4.w, w4.w, acc[3][3]);
    }
  }
  if (tx == 0) {
    Dl[uy * 4 + 0] = d0; Dl[uy * 4 + 1] = d1;
    Dl[uy * 4 + 2] = d2; Dl[uy * 4 + 3] = d3;
  }
  __syncthreads();
#pragma unroll
  for (int j = 0; j < 4; ++j) {
    int u = uy * 4 + j;
    float dinv = 1.0f / Dl[u];
    float4 o;
    o.x = fmaf(acc[j][0], dinv, bp[tx * 4 + 0]);
    o.y = fmaf(acc[j][1], dinv, bp[tx * 4 + 1]);
    o.z = fmaf(acc[j][2], dinv, bp[tx * 4 + 2]);
    o.w = fmaf(acc[j][3], dinv, bp[tx * 4 + 3]);
    *(float4*)&out[(((size_t)(b * TT + t) * UU + u) * NV) + tx * 4] = o;
  }
}

extern "C" void kernel_launch(void* const* d_in, const int* in_sizes, int n_in,
                              void* d_out, int out_size, void* d_ws, size_t ws_size,
                              hipStream_t stream) {
  (void)in_sizes; (void)n_in; (void)out_size; (void)ws_size;
  const float* encoder_inp   = (const float*)d_in[0];
  const int*   pred_inp      = (const int*)d_in[1];
  const float* encoder_state = (const float*)d_in[2];
  const float* enc_W0 = (const float*)d_in[3];
  const float* enc_U0 = (const float*)d_in[4];
  const float* enc_b0 = (const float*)d_in[5];
  const float* enc_W1 = (const float*)d_in[6];
  const float* enc_U1 = (const float*)d_in[7];
  const float* enc_b1 = (const float*)d_in[8];
  const float* embed   = (const float*)d_in[9];
  const float* pred_W0 = (const float*)d_in[10];
  const float* pred_U0 = (const float*)d_in[11];
  const float* pred_b0 = (const float*)d_in[12];
  const float* pred_W1 = (const float*)d_in[13];
  const float* pred_U1 = (const float*)d_in[14];
  const float* pred_b1 = (const float*)d_in[15];
  const float* Wj = (const float*)d_in[16];
  const float* bj = (const float*)d_in[17];
  const float* Ws = (const float*)d_in[18];
  const float* bs = (const float*)d_in[19];
  const float* Wp = (const float*)d_in[20];
  const float* bp = (const float*)d_in[21];
  float* outp = (float*)d_out;

  char* wsb = (char*)d_ws;
  size_t off = 0;
  auto alloc = [&](size_t bytes) -> void* {
    void* p = (void*)(wsb + off);
    off += (bytes + 255) & ~(size_t)255;
    return p;
  };
  float*    Ut_e0 = (float*)alloc((size_t)G4 * HD * 4);
  float*    Ut_e1 = (float*)alloc((size_t)G4 * HD * 4);
  ushort_t* Ut_p0 = (ushort_t*)alloc((size_t)G4 * HD * 2);
  ushort_t* Ut_p1 = (ushort_t*)alloc((size_t)G4 * HD * 2);
  float* xg_e0 = (float*)alloc((size_t)NB * TT * G4 * 4);
  float* ptab  = (float*)alloc((size_t)NV * G4 * 4);
  float* xg_e1 = (float*)alloc((size_t)NB * TT * G4 * 4);
  float* xg_p1 = (float*)alloc((size_t)NB * UU * G4 * 4);
  float* h0s  = (float*)alloc((size_t)NB * TT * HD * 4);
  float* hp0s = (float*)alloc((size_t)NB * UU * HD * 4);
  float* h1s  = (float*)alloc((size_t)NB * TT * HD * 4);
  float* hp1s = (float*)alloc((size_t)NB * UU * HD * 4);
  float* xjb = (float*)alloc((size_t)NB * TT * JD * 4);
  float* pjb = (float*)alloc((size_t)NB * UU * JD * 4);
  float* xsb = (float*)alloc((size_t)NB * TT * SMAXD * 4);
  float* psb = (float*)alloc((size_t)NB * UU * SMAXD * 4);
  float* csb = (float*)alloc((size_t)SMAXD * 4);
  float* hbufs = (float*)alloc((size_t)4 * 2 * NB * HD * 4);
  unsigned int* bars = (unsigned int*)alloc(512);

  float* hbufA_enc  = hbufs;
  float* hbufA_pred = hbufs + 2 * NB * HD;
  float* hbufC_enc  = hbufs + 4 * NB * HD;
  float* hbufC_pred = hbufs + 6 * NB * HD;

  hipMemsetAsync(hbufs, 0, (size_t)4 * 2 * NB * HD * 4, stream);
  hipMemsetAsync(bars, 0, 512, stream);
  hipMemcpyAsync(hbufA_enc, encoder_state, (size_t)NB * HD * 4, hipMemcpyDeviceToDevice, stream);
  hipMemcpyAsync(hbufC_enc, encoder_state, (size_t)NB * HD * 4, hipMemcpyDeviceToDevice, stream);

  dim3 tb(32, 8);
  transpose_f32 <<<dim3(G4 / 32, HD / 32), tb, 0, stream>>>(enc_U0, Ut_e0, HD, G4);
  transpose_f32 <<<dim3(G4 / 32, HD / 32), tb, 0, stream>>>(enc_U1, Ut_e1, HD, G4);
  transpose_bf16<<<dim3(G4 / 32, HD / 32), tb, 0, stream>>>(pred_U0, Ut_p0, HD, G4);
  transpose_bf16<<<dim3(G4 / 32, HD / 32), tb, 0, stream>>>(pred_U1, Ut_p1, HD, G4);

  inproj_kernel<<<NB * TT, 256, 0, stream>>>(encoder_inp, enc_W0, enc_b0, xg_e0, NFEAT);
  inproj_kernel<<<NV, 256, 0, stream>>>(embed, pred_W0, pred_b0, ptab, 64);

  // phase 1: enc0 (blocks 0..127) || pred0 (blocks 128..255)
  lstm_kernel<<<256, 256, 0, stream>>>(
      xg_e0, TT, Ut_e0, encoder_state + NB * HD, h0s, hbufA_enc, nullptr,
      ptab, UU, pred_inp, Ut_p0, hp0s, hbufA_pred, bars);

  // layer-1 input projections (batched)
  gemm_kernel<<<dim3(G4 / 64, (NB * TT) / 64), 256, 0, stream>>>(h0s, enc_W1, enc_b1, xg_e1, NB * TT, G4, HD);
  gemm_kernel<<<dim3(G4 / 64, (NB * UU) / 64), 256, 0, stream>>>(hp0s, pred_W1, pred_b1, xg_p1, NB * UU, G4, HD);

  // phase 2: enc1 || pred1 ; enc1 writes final state to d_out tail
  lstm_kernel<<<256, 256, 0, stream>>>(
      xg_e1, TT, Ut_e1, encoder_state + NB * HD, h1s, hbufC_enc,
      outp + (size_t)NB * TT * UU * NV,
      xg_p1, UU, nullptr, Ut_p1, hp1s, hbufC_pred, bars + 64);

  // factored joint: xs = (x@Wj)@Ws ; ps = (p@Wj)@Ws ; cs = bj@Ws + bs
  gemm_kernel<<<dim3(JD / 64, (NB * TT) / 64), 256, 0, stream>>>(h1s, Wj, nullptr, xjb, NB * TT, JD, HD);
  gemm_kernel<<<dim3(JD / 64, (NB * UU) / 64), 256, 0, stream>>>(hp1s, Wj, nullptr, pjb, NB * UU, JD, HD);
  gemm_kernel<<<dim3(SMAXD / 64, (NB * TT) / 64), 256, 0, stream>>>(xjb, Ws, nullptr, xsb, NB * TT, SMAXD, JD);
  gemm_kernel<<<dim3(SMAXD / 64, (NB * UU) / 64), 256, 0, stream>>>(pjb, Ws, nullptr, psb, NB * UU, SMAXD, JD);
  cs_kernel<<<SMAXD / 256, 256, 0, stream>>>(bj, Ws, bs, csb);

  final_kernel<<<NB * TT, 256, 0, stream>>>(xsb, psb, csb, Wp, bp, outp);
}

// Round 5
// 6741.050 us; speedup vs baseline: 1.0261x; 1.0261x over previous
//
#include <hip/hip_runtime.h>
#include <stdint.h>

typedef unsigned short ushort_t;

#define HD 1024
#define G4 4096
#define NB 4
#define TT 128
#define UU 64
#define NFEAT 80
#define SMAXD 4096
#define JD 640
#define NV 64

static __device__ __forceinline__ float lo2f(uint32_t u) {
  union { uint32_t i; float f; } v; v.i = u << 16; return v.f;
}
static __device__ __forceinline__ float hi2f(uint32_t u) {
  union { uint32_t i; float f; } v; v.i = u & 0xffff0000u; return v.f;
}
static __device__ __forceinline__ ushort_t f2bf(float f) {
  union { uint32_t i; float f; } v; v.f = f;
  return (ushort_t)((v.i + 0x7fffu + ((v.i >> 16) & 1u)) >> 16);
}

// ---------------- transpose: src [K,N] f32 -> dst [N,K] ----------------
__global__ void transpose_f32(const float* __restrict__ src, float* __restrict__ dst,
                              int K, int N) {
  __shared__ float tile[32][33];
  int n0 = blockIdx.x * 32, k0 = blockIdx.y * 32;
  int tx = threadIdx.x, ty = threadIdx.y;
#pragma unroll
  for (int j = 0; j < 32; j += 8)
    tile[ty + j][tx] = src[(size_t)(k0 + ty + j) * N + n0 + tx];
  __syncthreads();
#pragma unroll
  for (int j = 0; j < 32; j += 8)
    dst[(size_t)(n0 + ty + j) * K + k0 + tx] = tile[tx][ty + j];
}

__global__ void transpose_bf16(const float* __restrict__ src, ushort_t* __restrict__ dst,
                               int K, int N) {
  __shared__ float tile[32][33];
  int n0 = blockIdx.x * 32, k0 = blockIdx.y * 32;
  int tx = threadIdx.x, ty = threadIdx.y;
#pragma unroll
  for (int j = 0; j < 32; j += 8)
    tile[ty + j][tx] = src[(size_t)(k0 + ty + j) * N + n0 + tx];
  __syncthreads();
#pragma unroll
  for (int j = 0; j < 32; j += 8)
    dst[(size_t)(n0 + ty + j) * K + k0 + tx] = f2bf(tile[tx][ty + j]);
}

// -------- input projection: C[m,:] = X[m,:K] @ W[K,4096] + bias (one block per row m)
__global__ __launch_bounds__(256) void inproj_kernel(
    const float* __restrict__ X, const float* __restrict__ W,
    const float* __restrict__ bias, float* __restrict__ C, int K) {
  __shared__ float xls[JD];
  int m = blockIdx.x;
  int tid = threadIdx.x;
  for (int i = tid; i < K; i += 256) xls[i] = X[(size_t)m * K + i];
  __syncthreads();
  for (int c = tid; c < G4; c += 256) {
    float acc = bias[c];
    for (int k = 0; k < K; ++k) acc = fmaf(xls[k], W[(size_t)k * G4 + c], acc);
    C[(size_t)m * G4 + c] = acc;
  }
}

// -------- cs[c] = bs[c] + sum_k bj[k] * Ws[k,c] ; grid 16 x 256
__global__ __launch_bounds__(256) void cs_kernel(const float* __restrict__ bj,
                                                 const float* __restrict__ Ws,
                                                 const float* __restrict__ bs,
                                                 float* __restrict__ cs) {
  __shared__ float bl[JD];
  int tid = threadIdx.x;
  for (int i = tid; i < JD; i += 256) bl[i] = bj[i];
  __syncthreads();
  int c = blockIdx.x * 256 + tid;
  float acc = bs[c];
  for (int k = 0; k < JD; ++k) acc = fmaf(bl[k], Ws[(size_t)k * G4 + c], acc);
  cs[c] = acc;
}

// -------- generic GEMM: C[M,N] = A[M,K] @ B[K,N] (+ bias over N). 64x64 tile, BK=32.
__global__ __launch_bounds__(256) void gemm_kernel(
    const float* __restrict__ A, const float* __restrict__ Bm,
    const float* __restrict__ bias, float* __restrict__ C,
    int M, int N, int K) {
  __shared__ float As[32][68];
  __shared__ float Bs[32][68];
  int n0 = blockIdx.x * 64, m0 = blockIdx.y * 64;
  int tid = threadIdx.x;
  int tx = tid & 15, ty = tid >> 4;
  float acc[4][4] = {};
  for (int k0 = 0; k0 < K; k0 += 32) {
#pragma unroll
    for (int i = 0; i < 8; ++i) {
      int idx = tid + i * 256;
      int ml = idx >> 5, kl = idx & 31;
      As[kl][ml] = A[(size_t)(m0 + ml) * K + k0 + kl];
      int kl2 = idx >> 6, nl = idx & 63;
      Bs[kl2][nl] = Bm[(size_t)(k0 + kl2) * N + n0 + nl];
    }
    __syncthreads();
#pragma unroll 8
    for (int k = 0; k < 32; ++k) {
      float4 a4 = *(const float4*)&As[k][ty * 4];
      float4 b4 = *(const float4*)&Bs[k][tx * 4];
      acc[0][0] = fmaf(a4.x, b4.x, acc[0][0]);
      acc[0][1] = fmaf(a4.x, b4.y, acc[0][1]);
      acc[0][2] = fmaf(a4.x, b4.z, acc[0][2]);
      acc[0][3] = fmaf(a4.x, b4.w, acc[0][3]);
      acc[1][0] = fmaf(a4.y, b4.x, acc[1][0]);
      acc[1][1] = fmaf(a4.y, b4.y, acc[1][1]);
      acc[1][2] = fmaf(a4.y, b4.z, acc[1][2]);
      acc[1][3] = fmaf(a4.y, b4.w, acc[1][3]);
      acc[2][0] = fmaf(a4.z, b4.x, acc[2][0]);
      acc[2][1] = fmaf(a4.z, b4.y, acc[2][1]);
      acc[2][2] = fmaf(a4.z, b4.z, acc[2][2]);
      acc[2][3] = fmaf(a4.z, b4.w, acc[2][3]);
      acc[3][0] = fmaf(a4.w, b4.x, acc[3][0]);
      acc[3][1] = fmaf(a4.w, b4.y, acc[3][1]);
      acc[3][2] = fmaf(a4.w, b4.z, acc[3][2]);
      acc[3][3] = fmaf(a4.w, b4.w, acc[3][3]);
    }
    __syncthreads();
  }
  float b0 = 0.f, b1 = 0.f, b2 = 0.f, b3 = 0.f;
  if (bias) {
    b0 = bias[n0 + tx * 4 + 0]; b1 = bias[n0 + tx * 4 + 1];
    b2 = bias[n0 + tx * 4 + 2]; b3 = bias[n0 + tx * 4 + 3];
  }
#pragma unroll
  for (int i = 0; i < 4; ++i) {
    float4 o;
    o.x = acc[i][0] + b0; o.y = acc[i][1] + b1; o.z = acc[i][2] + b2; o.w = acc[i][3] + b3;
    *(float4*)&C[(size_t)(m0 + ty * 4 + i) * N + n0 + tx * 4] = o;
  }
}

// -------- persistent dual-layer LSTM stepper, 256 blocks x 256 threads.
// blocks [0,128): group A (encoder, U fp32); blocks [128,256): group B (pred, U bf16).
// U column slice lives in REGISTERS (u[128] per thread). Per-group all-to-all
// flag barrier (no contended atomics): block p release-stores epoch to
// flags[p*32]; threads tid<128 each poll one peer flag.
__global__ __launch_bounds__(256, 1) void lstm_kernel(
    const float* __restrict__ xgA, int lenA,
    const float* __restrict__ UtA,     // [4096][1024] f32 (transposed)
    const float* __restrict__ cinitA,  // [4*1024] or nullptr
    float* __restrict__ hseqA,         // [4, lenA, 1024]
    float* __restrict__ hbufA,         // [2][4*1024]
    float* __restrict__ finalA,        // nullptr or [2][4][1024] (h then c)
    const float* __restrict__ xgB, int lenB,  // table [64,4096] if tokB else [4,lenB,4096]
    const int* __restrict__ tokB,
    const ushort_t* __restrict__ UtB,  // [4096][1024] bf16 (transposed)
    float* __restrict__ hseqB,
    float* __restrict__ hbufB,
    unsigned int* __restrict__ flagsA,
    unsigned int* __restrict__ flagsB) {
  __shared__ float hprev[NB][HD];     // 16KB
  __shared__ float red[8][NB][32];    // 4KB
  __shared__ float gl[NB][32];
  __shared__ float cst[NB][8];
  int blk = blockIdx.x;
  int isA = (blk < 128) ? 1 : 0;
  int p = blk & 127;
  int tid = threadIdx.x;
  int c = tid & 31, s = tid >> 5;     // col-local, k-slice
  int len = isA ? lenA : lenB;
  const float* xg = isA ? xgA : xgB;
  float* hseq = isA ? hseqA : hseqB;
  float* hbuf = isA ? hbufA : hbufB;
  unsigned int* flags = isA ? flagsA : flagsB;

  if (tid < 32) {
    int bb = tid >> 3, hh = tid & 7;
    cst[bb][hh] = (isA && cinitA) ? cinitA[bb * HD + p * 8 + hh] : 0.0f;
  }

  int gate = c >> 3, hic = c & 7;
  int ucol = gate * HD + p * 8 + hic;
  int kb = s * 128;

  // ---- hoist this thread's U slice (128 floats) into registers ----
  float u[128];
  if (isA) {
    const float4* ur = (const float4*)(UtA + (size_t)ucol * HD + kb);
#pragma unroll
    for (int i = 0; i < 32; ++i) ((float4*)u)[i] = ur[i];
  } else {
    const uint4* ur = (const uint4*)(UtB + (size_t)ucol * HD + kb);
#pragma unroll
    for (int i = 0; i < 16; ++i) {
      uint4 q = ur[i];
      u[i * 8 + 0] = lo2f(q.x); u[i * 8 + 1] = hi2f(q.x);
      u[i * 8 + 2] = lo2f(q.y); u[i * 8 + 3] = hi2f(q.y);
      u[i * 8 + 4] = lo2f(q.z); u[i * 8 + 5] = hi2f(q.z);
      u[i * 8 + 6] = lo2f(q.w); u[i * 8 + 7] = hi2f(q.w);
    }
  }

  for (int t = 0; t < len; ++t) {
    int par = t & 1;
    const float* hsrc = hbuf + par * (NB * HD);
    {
      float4* hp4 = (float4*)&hprev[0][0];
      const float4* hs4 = (const float4*)hsrc;
#pragma unroll
      for (int i = 0; i < 4; ++i) hp4[tid + i * 256] = hs4[tid + i * 256];
    }
    __syncthreads();

    float aa[4] = {0.f, 0.f, 0.f, 0.f};
#pragma unroll
    for (int k4 = 0; k4 < 32; ++k4) {
#pragma unroll
      for (int bb = 0; bb < 4; ++bb) {
        float4 h4 = *(const float4*)&hprev[bb][kb + k4 * 4];
        aa[bb] = fmaf(u[k4 * 4 + 0], h4.x, aa[bb]);
        aa[bb] = fmaf(u[k4 * 4 + 1], h4.y, aa[bb]);
        aa[bb] = fmaf(u[k4 * 4 + 2], h4.z, aa[bb]);
        aa[bb] = fmaf(u[k4 * 4 + 3], h4.w, aa[bb]);
      }
    }
    red[s][0][c] = aa[0]; red[s][1][c] = aa[1];
    red[s][2][c] = aa[2]; red[s][3][c] = aa[3];
    __syncthreads();

    if (tid < 128) {
      int bb = tid >> 5, cc = tid & 31;
      float g = red[0][bb][cc] + red[1][bb][cc] + red[2][bb][cc] + red[3][bb][cc] +
                red[4][bb][cc] + red[5][bb][cc] + red[6][bb][cc] + red[7][bb][cc];
      int gg = cc >> 3, hh = cc & 7;
      int uc = gg * HD + p * 8 + hh;
      float xv;
      if (!isA && tokB) {
        int token = tokB[bb * lenB + t];
        xv = xg[(size_t)token * G4 + uc];
      } else {
        xv = xg[((size_t)bb * len + t) * G4 + uc];
      }
      gl[bb][cc] = g + xv;
    }
    __syncthreads();

    if (tid < 32) {
      int bb = tid >> 3, hh = tid & 7;
      float gi = gl[bb][hh], gf = gl[bb][8 + hh], gc = gl[bb][16 + hh], go = gl[bb][24 + hh];
      float si = 1.0f / (1.0f + expf(-gi));
      float sf = 1.0f / (1.0f + expf(-gf));
      float so = 1.0f / (1.0f + expf(-go));
      float cN = sf * cst[bb][hh] + si * tanhf(gc);
      float hN = so * tanhf(cN);
      cst[bb][hh] = cN;
      int hidx = p * 8 + hh;
      hbuf[(par ^ 1) * (NB * HD) + bb * HD + hidx] = hN;
      hseq[((size_t)bb * len + t) * HD + hidx] = hN;
      if (isA && finalA && t == len - 1) {
        finalA[bb * HD + hidx] = hN;
        finalA[NB * HD + bb * HD + hidx] = cN;
      }
      __threadfence();
    }
    __syncthreads();

    if (t + 1 < len) {
      if (tid == 0)
        __hip_atomic_store(&flags[p * 32], (unsigned)(t + 1),
                           __ATOMIC_RELEASE, __HIP_MEMORY_SCOPE_AGENT);
      if (tid < 128) {
        while (__hip_atomic_load(&flags[tid * 32], __ATOMIC_RELAXED,
                                 __HIP_MEMORY_SCOPE_AGENT) < (unsigned)(t + 1)) {
          __builtin_amdgcn_s_sleep(1);
        }
      }
      __syncthreads();
      __threadfence();   // acquire side: make peers' h stores visible
    }
  }
}

// -------- fused softmax + s@Wp + bp. One block per (b,t); 64u x 64v output tile.
__global__ __launch_bounds__(256) void final_kernel(
    const float* __restrict__ xsA, const float* __restrict__ psA,
    const float* __restrict__ csA, const float* __restrict__ Wp,
    const float* __restrict__ bp, float* __restrict__ out) {
  __shared__ float xc[SMAXD];       // 16KB
  __shared__ float el[64][68];      // 17.4KB  e[k][u]
  __shared__ float wl[64][68];      // 17.4KB  Wp[k][v]
  __shared__ float Dl[64];
  int bt = blockIdx.x;
  int b = bt >> 7, t = bt & 127;
  int tid = threadIdx.x;
  int tx = tid & 15, uy = tid >> 4;
  for (int i = tid; i < SMAXD; i += 256) xc[i] = xsA[(size_t)bt * SMAXD + i] + csA[i];
  const float* psrow = psA + (size_t)b * UU * SMAXD;
  float acc[4][4] = {};
  float d0 = 0.f, d1 = 0.f, d2 = 0.f, d3 = 0.f;
  for (int k0 = 0; k0 < SMAXD; k0 += 64) {
    __syncthreads();
#pragma unroll
    for (int i = 0; i < 16; ++i) {
      int idx = tid + i * 256;
      int kl = idx >> 6, vl = idx & 63;
      wl[kl][vl] = Wp[(size_t)(k0 + kl) * NV + vl];
    }
#pragma unroll
    for (int i = 0; i < 16; ++i) {
      int idx = tid + i * 256;
      int u = idx >> 6, kl = idx & 63;
      float l = xc[k0 + kl] + psrow[(size_t)u * SMAXD + k0 + kl];
      el[kl][u] = __expf(l);   // logits are tiny; shared-shift softmax needs no max pass
    }
    __syncthreads();
#pragma unroll 4
    for (int k = 0; k < 64; ++k) {
      float4 e4 = *(const float4*)&el[k][uy * 4];
      float4 w4 = *(const float4*)&wl[k][tx * 4];
      d0 += e4.x; d1 += e4.y; d2 += e4.z; d3 += e4.w;
      acc[0][0] = fmaf(e4.x, w4.x, acc[0][0]);
      acc[0][1] = fmaf(e4.x, w4.y, acc[0][1]);
      acc[0][2] = fmaf(e4.x, w4.z, acc[0][2]);
      acc[0][3] = fmaf(e4.x, w4.w, acc[0][3]);
      acc[1][0] = fmaf(e4.y, w4.x, acc[1][0]);
      acc[1][1] = fmaf(e4.y, w4.y, acc[1][1]);
      acc[1][2] = fmaf(e4.y, w4.z, acc[1][2]);
      acc[1][3] = fmaf(e4.y, w4.w, acc[1][3]);
      acc[2][0] = fmaf(e4.z, w4.x, acc[2][0]);
      acc[2][1] = fmaf(e4.z, w4.y, acc[2][1]);
      acc[2][2] = fmaf(e4.z, w4.z, acc[2][2]);
      acc[2][3] = fmaf(e4.z, w4.w, acc[2][3]);
      acc[3][0] = fmaf(e4.w, w4.x, acc[3][0]);
      acc[3][1] = fmaf(e4.w, w4.y, acc[3][1]);
      acc[3][2] = fmaf(e4.w, w4.z, acc[3][2]);
      acc[3][3] = fmaf(e4.w, w4.w, acc[3][3]);
    }
  }
  if (tx == 0) {
    Dl[uy * 4 + 0] = d0; Dl[uy * 4 + 1] = d1;
    Dl[uy * 4 + 2] = d2; Dl[uy * 4 + 3] = d3;
  }
  __syncthreads();
#pragma unroll
  for (int j = 0; j < 4; ++j) {
    int u = uy * 4 + j;
    float dinv = 1.0f / Dl[u];
    float4 o;
    o.x = fmaf(acc[j][0], dinv, bp[tx * 4 + 0]);
    o.y = fmaf(acc[j][1], dinv, bp[tx * 4 + 1]);
    o.z = fmaf(acc[j][2], dinv, bp[tx * 4 + 2]);
    o.w = fmaf(acc[j][3], dinv, bp[tx * 4 + 3]);
    *(float4*)&out[(((size_t)(b * TT + t) * UU + u) * NV) + tx * 4] = o;
  }
}

extern "C" void kernel_launch(void* const* d_in, const int* in_sizes, int n_in,
                              void* d_out, int out_size, void* d_ws, size_t ws_size,
                              hipStream_t stream) {
  (void)in_sizes; (void)n_in; (void)out_size; (void)ws_size;
  const float* encoder_inp   = (const float*)d_in[0];
  const int*   pred_inp      = (const int*)d_in[1];
  const float* encoder_state = (const float*)d_in[2];
  const float* enc_W0 = (const float*)d_in[3];
  const float* enc_U0 = (const float*)d_in[4];
  const float* enc_b0 = (const float*)d_in[5];
  const float* enc_W1 = (const float*)d_in[6];
  const float* enc_U1 = (const float*)d_in[7];
  const float* enc_b1 = (const float*)d_in[8];
  const float* embed   = (const float*)d_in[9];
  const float* pred_W0 = (const float*)d_in[10];
  const float* pred_U0 = (const float*)d_in[11];
  const float* pred_b0 = (const float*)d_in[12];
  const float* pred_W1 = (const float*)d_in[13];
  const float* pred_U1 = (const float*)d_in[14];
  const float* pred_b1 = (const float*)d_in[15];
  const float* Wj = (const float*)d_in[16];
  const float* bj = (const float*)d_in[17];
  const float* Ws = (const float*)d_in[18];
  const float* bs = (const float*)d_in[19];
  const float* Wp = (const float*)d_in[20];
  const float* bp = (const float*)d_in[21];
  float* outp = (float*)d_out;

  char* wsb = (char*)d_ws;
  size_t off = 0;
  auto alloc = [&](size_t bytes) -> void* {
    void* p = (void*)(wsb + off);
    off += (bytes + 255) & ~(size_t)255;
    return p;
  };
  float*    Ut_e0 = (float*)alloc((size_t)G4 * HD * 4);
  float*    Ut_e1 = (float*)alloc((size_t)G4 * HD * 4);
  ushort_t* Ut_p0 = (ushort_t*)alloc((size_t)G4 * HD * 2);
  ushort_t* Ut_p1 = (ushort_t*)alloc((size_t)G4 * HD * 2);
  float* xg_e0 = (float*)alloc((size_t)NB * TT * G4 * 4);
  float* ptab  = (float*)alloc((size_t)NV * G4 * 4);
  float* xg_e1 = (float*)alloc((size_t)NB * TT * G4 * 4);
  float* xg_p1 = (float*)alloc((size_t)NB * UU * G4 * 4);
  float* h0s  = (float*)alloc((size_t)NB * TT * HD * 4);
  float* hp0s = (float*)alloc((size_t)NB * UU * HD * 4);
  float* h1s  = (float*)alloc((size_t)NB * TT * HD * 4);
  float* hp1s = (float*)alloc((size_t)NB * UU * HD * 4);
  float* xjb = (float*)alloc((size_t)NB * TT * JD * 4);
  float* pjb = (float*)alloc((size_t)NB * UU * JD * 4);
  float* xsb = (float*)alloc((size_t)NB * TT * SMAXD * 4);
  float* psb = (float*)alloc((size_t)NB * UU * SMAXD * 4);
  float* csb = (float*)alloc((size_t)SMAXD * 4);
  float* hbufs = (float*)alloc((size_t)4 * 2 * NB * HD * 4);
  unsigned int* bars = (unsigned int*)alloc((size_t)4 * 128 * 32 * 4);  // 4 groups of 128 padded flags

  float* hbufA_enc  = hbufs;
  float* hbufA_pred = hbufs + 2 * NB * HD;
  float* hbufC_enc  = hbufs + 4 * NB * HD;
  float* hbufC_pred = hbufs + 6 * NB * HD;

  unsigned int* flags_e0 = bars;
  unsigned int* flags_p0 = bars + 1 * 128 * 32;
  unsigned int* flags_e1 = bars + 2 * 128 * 32;
  unsigned int* flags_p1 = bars + 3 * 128 * 32;

  hipMemsetAsync(hbufs, 0, (size_t)4 * 2 * NB * HD * 4, stream);
  hipMemsetAsync(bars, 0, (size_t)4 * 128 * 32 * 4, stream);
  hipMemcpyAsync(hbufA_enc, encoder_state, (size_t)NB * HD * 4, hipMemcpyDeviceToDevice, stream);
  hipMemcpyAsync(hbufC_enc, encoder_state, (size_t)NB * HD * 4, hipMemcpyDeviceToDevice, stream);

  dim3 tb(32, 8);
  transpose_f32 <<<dim3(G4 / 32, HD / 32), tb, 0, stream>>>(enc_U0, Ut_e0, HD, G4);
  transpose_f32 <<<dim3(G4 / 32, HD / 32), tb, 0, stream>>>(enc_U1, Ut_e1, HD, G4);
  transpose_bf16<<<dim3(G4 / 32, HD / 32), tb, 0, stream>>>(pred_U0, Ut_p0, HD, G4);
  transpose_bf16<<<dim3(G4 / 32, HD / 32), tb, 0, stream>>>(pred_U1, Ut_p1, HD, G4);

  inproj_kernel<<<NB * TT, 256, 0, stream>>>(encoder_inp, enc_W0, enc_b0, xg_e0, NFEAT);
  inproj_kernel<<<NV, 256, 0, stream>>>(embed, pred_W0, pred_b0, ptab, 64);

  // phase 1: enc0 (blocks 0..127) || pred0 (blocks 128..255)
  lstm_kernel<<<256, 256, 0, stream>>>(
      xg_e0, TT, Ut_e0, encoder_state + NB * HD, h0s, hbufA_enc, nullptr,
      ptab, UU, pred_inp, Ut_p0, hp0s, hbufA_pred, flags_e0, flags_p0);

  // layer-1 input projections (batched)
  gemm_kernel<<<dim3(G4 / 64, (NB * TT) / 64), 256, 0, stream>>>(h0s, enc_W1, enc_b1, xg_e1, NB * TT, G4, HD);
  gemm_kernel<<<dim3(G4 / 64, (NB * UU) / 64), 256, 0, stream>>>(hp0s, pred_W1, pred_b1, xg_p1, NB * UU, G4, HD);

  // phase 2: enc1 || pred1 ; enc1 writes final state to d_out tail
  lstm_kernel<<<256, 256, 0, stream>>>(
      xg_e1, TT, Ut_e1, encoder_state + NB * HD, h1s, hbufC_enc,
      outp + (size_t)NB * TT * UU * NV,
      xg_p1, UU, nullptr, Ut_p1, hp1s, hbufC_pred, flags_e1, flags_p1);

  // factored joint: xs = (x@Wj)@Ws ; ps = (p@Wj)@Ws ; cs = bj@Ws + bs
  gemm_kernel<<<dim3(JD / 64, (NB * TT) / 64), 256, 0, stream>>>(h1s, Wj, nullptr, xjb, NB * TT, JD, HD);
  gemm_kernel<<<dim3(JD / 64, (NB * UU) / 64), 256, 0, stream>>>(hp1s, Wj, nullptr, pjb, NB * UU, JD, HD);
  gemm_kernel<<<dim3(SMAXD / 64, (NB * TT) / 64), 256, 0, stream>>>(xjb, Ws, nullptr, xsb, NB * TT, SMAXD, JD);
  gemm_kernel<<<dim3(SMAXD / 64, (NB * UU) / 64), 256, 0, stream>>>(pjb, Ws, nullptr, psb, NB * UU, SMAXD, JD);
  cs_kernel<<<SMAXD / 256, 256, 0, stream>>>(bj, Ws, bs, csb);

  final_kernel<<<NB * TT, 256, 0, stream>>>(xsb, psb, csb, Wp, bp, outp);
}

// Round 7
// 3695.163 us; speedup vs baseline: 1.8719x; 1.8243x over previous
//
#include <hip/hip_runtime.h>
#include <stdint.h>

typedef unsigned short ushort_t;

#define HD 1024
#define G4 4096
#define NB 4
#define TT 128
#define UU 64
#define NFEAT 80
#define SMAXD 4096
#define JD 640
#define NV 64

static __device__ __forceinline__ float lo2f(uint32_t u) {
  union { uint32_t i; float f; } v; v.i = u << 16; return v.f;
}
static __device__ __forceinline__ float hi2f(uint32_t u) {
  union { uint32_t i; float f; } v; v.i = u & 0xffff0000u; return v.f;
}
static __device__ __forceinline__ ushort_t f2bf(float f) {
  union { uint32_t i; float f; } v; v.f = f;
  return (ushort_t)((v.i + 0x7fffu + ((v.i >> 16) & 1u)) >> 16);
}

// ---------------- transpose: src [K,N] f32 -> dst [N,K] ----------------
__global__ void transpose_f32(const float* __restrict__ src, float* __restrict__ dst,
                              int K, int N) {
  __shared__ float tile[32][33];
  int n0 = blockIdx.x * 32, k0 = blockIdx.y * 32;
  int tx = threadIdx.x, ty = threadIdx.y;
#pragma unroll
  for (int j = 0; j < 32; j += 8)
    tile[ty + j][tx] = src[(size_t)(k0 + ty + j) * N + n0 + tx];
  __syncthreads();
#pragma unroll
  for (int j = 0; j < 32; j += 8)
    dst[(size_t)(n0 + ty + j) * K + k0 + tx] = tile[tx][ty + j];
}

__global__ void transpose_bf16(const float* __restrict__ src, ushort_t* __restrict__ dst,
                               int K, int N) {
  __shared__ float tile[32][33];
  int n0 = blockIdx.x * 32, k0 = blockIdx.y * 32;
  int tx = threadIdx.x, ty = threadIdx.y;
#pragma unroll
  for (int j = 0; j < 32; j += 8)
    tile[ty + j][tx] = src[(size_t)(k0 + ty + j) * N + n0 + tx];
  __syncthreads();
#pragma unroll
  for (int j = 0; j < 32; j += 8)
    dst[(size_t)(n0 + ty + j) * K + k0 + tx] = f2bf(tile[tx][ty + j]);
}

// -------- input projection: C[m,:] = X[m,:K] @ W[K,4096] + bias (one block per row m)
__global__ __launch_bounds__(256) void inproj_kernel(
    const float* __restrict__ X, const float* __restrict__ W,
    const float* __restrict__ bias, float* __restrict__ C, int K) {
  __shared__ float xls[JD];
  int m = blockIdx.x;
  int tid = threadIdx.x;
  for (int i = tid; i < K; i += 256) xls[i] = X[(size_t)m * K + i];
  __syncthreads();
  for (int c = tid; c < G4; c += 256) {
    float acc = bias[c];
    for (int k = 0; k < K; ++k) acc = fmaf(xls[k], W[(size_t)k * G4 + c], acc);
    C[(size_t)m * G4 + c] = acc;
  }
}

// -------- cs[c] = bs[c] + sum_k bj[k] * Ws[k,c] ; grid 16 x 256
__global__ __launch_bounds__(256) void cs_kernel(const float* __restrict__ bj,
                                                 const float* __restrict__ Ws,
                                                 const float* __restrict__ bs,
                                                 float* __restrict__ cs) {
  __shared__ float bl[JD];
  int tid = threadIdx.x;
  for (int i = tid; i < JD; i += 256) bl[i] = bj[i];
  __syncthreads();
  int c = blockIdx.x * 256 + tid;
  float acc = bs[c];
  for (int k = 0; k < JD; ++k) acc = fmaf(bl[k], Ws[(size_t)k * G4 + c], acc);
  cs[c] = acc;
}

// -------- generic GEMM: C[M,N] = A[M,K] @ B[K,N] (+ bias over N). 64x64 tile, BK=32.
__global__ __launch_bounds__(256) void gemm_kernel(
    const float* __restrict__ A, const float* __restrict__ Bm,
    const float* __restrict__ bias, float* __restrict__ C,
    int M, int N, int K) {
  __shared__ float As[32][68];
  __shared__ float Bs[32][68];
  int n0 = blockIdx.x * 64, m0 = blockIdx.y * 64;
  int tid = threadIdx.x;
  int tx = tid & 15, ty = tid >> 4;
  float acc[4][4] = {};
  for (int k0 = 0; k0 < K; k0 += 32) {
#pragma unroll
    for (int i = 0; i < 8; ++i) {
      int idx = tid + i * 256;
      int ml = idx >> 5, kl = idx & 31;
      As[kl][ml] = A[(size_t)(m0 + ml) * K + k0 + kl];
      int kl2 = idx >> 6, nl = idx & 63;
      Bs[kl2][nl] = Bm[(size_t)(k0 + kl2) * N + n0 + nl];
    }
    __syncthreads();
#pragma unroll 8
    for (int k = 0; k < 32; ++k) {
      float4 a4 = *(const float4*)&As[k][ty * 4];
      float4 b4 = *(const float4*)&Bs[k][tx * 4];
      acc[0][0] = fmaf(a4.x, b4.x, acc[0][0]);
      acc[0][1] = fmaf(a4.x, b4.y, acc[0][1]);
      acc[0][2] = fmaf(a4.x, b4.z, acc[0][2]);
      acc[0][3] = fmaf(a4.x, b4.w, acc[0][3]);
      acc[1][0] = fmaf(a4.y, b4.x, acc[1][0]);
      acc[1][1] = fmaf(a4.y, b4.y, acc[1][1]);
      acc[1][2] = fmaf(a4.y, b4.z, acc[1][2]);
      acc[1][3] = fmaf(a4.y, b4.w, acc[1][3]);
      acc[2][0] = fmaf(a4.z, b4.x, acc[2][0]);
      acc[2][1] = fmaf(a4.z, b4.y, acc[2][1]);
      acc[2][2] = fmaf(a4.z, b4.z, acc[2][2]);
      acc[2][3] = fmaf(a4.z, b4.w, acc[2][3]);
      acc[3][0] = fmaf(a4.w, b4.x, acc[3][0]);
      acc[3][1] = fmaf(a4.w, b4.y, acc[3][1]);
      acc[3][2] = fmaf(a4.w, b4.z, acc[3][2]);
      acc[3][3] = fmaf(a4.w, b4.w, acc[3][3]);
    }
    __syncthreads();
  }
  float b0 = 0.f, b1 = 0.f, b2 = 0.f, b3 = 0.f;
  if (bias) {
    b0 = bias[n0 + tx * 4 + 0]; b1 = bias[n0 + tx * 4 + 1];
    b2 = bias[n0 + tx * 4 + 2]; b3 = bias[n0 + tx * 4 + 3];
  }
#pragma unroll
  for (int i = 0; i < 4; ++i) {
    float4 o;
    o.x = acc[i][0] + b0; o.y = acc[i][1] + b1; o.z = acc[i][2] + b2; o.w = acc[i][3] + b3;
    *(float4*)&C[(size_t)(m0 + ty * 4 + i) * N + n0 + tx * 4] = o;
  }
}

// -------- persistent dual-layer LSTM stepper, 256 blocks x 256 threads.
// blocks [0,128): group A (encoder, U fp32); blocks [128,256): group B (pred, U bf16).
// Cross-block h exchange via RELAXED AGENT-SCOPE atomics (sc1 write-through /
// cache-bypass to LLC) -- NO __threadfence / release-acquire, so no per-step
// buffer_wbl2 / buffer_inv L2 maintenance. Ordering h-stores -> flag-store is
// s_waitcnt vmcnt(0) (also implied by __syncthreads drain).
__global__ __launch_bounds__(256, 1) void lstm_kernel(
    const float* __restrict__ xgA, int lenA,
    const float* __restrict__ UtA,     // [4096][1024] f32 (transposed)
    const float* __restrict__ cinitA,  // [4*1024] or nullptr
    float* __restrict__ hseqA,         // [4, lenA, 1024]
    float* __restrict__ hbufA,         // [2][4*1024]
    float* __restrict__ finalA,        // nullptr or [2][4][1024] (h then c)
    const float* __restrict__ xgB, int lenB,  // table [64,4096] if tokB else [4,lenB,4096]
    const int* __restrict__ tokB,
    const ushort_t* __restrict__ UtB,  // [4096][1024] bf16 (transposed)
    float* __restrict__ hseqB,
    float* __restrict__ hbufB,
    unsigned int* __restrict__ flagsA,
    unsigned int* __restrict__ flagsB) {
  __shared__ float hprev[NB][HD];     // 16KB
  __shared__ float red[8][NB][32];    // 4KB
  __shared__ float gl[NB][32];
  __shared__ float cst[NB][8];
  int blk = blockIdx.x;
  int isA = (blk < 128) ? 1 : 0;
  int p = blk & 127;
  int tid = threadIdx.x;
  int c = tid & 31, s = tid >> 5;     // col-local, k-slice
  int len = isA ? lenA : lenB;
  const float* xg = isA ? xgA : xgB;
  float* hseq = isA ? hseqA : hseqB;
  float* hbuf = isA ? hbufA : hbufB;
  unsigned int* flags = isA ? flagsA : flagsB;

  if (tid < 32) {
    int bb = tid >> 3, hh = tid & 7;
    cst[bb][hh] = (isA && cinitA) ? cinitA[bb * HD + p * 8 + hh] : 0.0f;
  }

  int gate = c >> 3, hic = c & 7;
  int ucol = gate * HD + p * 8 + hic;
  int kb = s * 128;

  // ---- hoist this thread's U slice (128 floats) into registers ----
  float u[128];
  if (isA) {
    const float4* ur = (const float4*)(UtA + (size_t)ucol * HD + kb);
#pragma unroll
    for (int i = 0; i < 32; ++i) ((float4*)u)[i] = ur[i];
  } else {
    const uint4* ur = (const uint4*)(UtB + (size_t)ucol * HD + kb);
#pragma unroll
    for (int i = 0; i < 16; ++i) {
      uint4 q = ur[i];
      u[i * 8 + 0] = lo2f(q.x); u[i * 8 + 1] = hi2f(q.x);
      u[i * 8 + 2] = lo2f(q.y); u[i * 8 + 3] = hi2f(q.y);
      u[i * 8 + 4] = lo2f(q.z); u[i * 8 + 5] = hi2f(q.z);
      u[i * 8 + 6] = lo2f(q.w); u[i * 8 + 7] = hi2f(q.w);
    }
  }

  for (int t = 0; t < len; ++t) {
    int par = t & 1;
    const float* hsrc = hbuf + par * (NB * HD);
    // gather fresh h from LLC (cache-bypassing relaxed agent loads)
    {
      float* hp = &hprev[0][0];
#pragma unroll
      for (int i = 0; i < 16; ++i) {
        int idx = tid + i * 256;
        hp[idx] = __hip_atomic_load(hsrc + idx, __ATOMIC_RELAXED,
                                    __HIP_MEMORY_SCOPE_AGENT);
      }
    }
    __syncthreads();

    float aa[4] = {0.f, 0.f, 0.f, 0.f};
#pragma unroll
    for (int k4 = 0; k4 < 32; ++k4) {
#pragma unroll
      for (int bb = 0; bb < 4; ++bb) {
        float4 h4 = *(const float4*)&hprev[bb][kb + k4 * 4];
        aa[bb] = fmaf(u[k4 * 4 + 0], h4.x, aa[bb]);
        aa[bb] = fmaf(u[k4 * 4 + 1], h4.y, aa[bb]);
        aa[bb] = fmaf(u[k4 * 4 + 2], h4.z, aa[bb]);
        aa[bb] = fmaf(u[k4 * 4 + 3], h4.w, aa[bb]);
      }
    }
    red[s][0][c] = aa[0]; red[s][1][c] = aa[1];
    red[s][2][c] = aa[2]; red[s][3][c] = aa[3];
    __syncthreads();

    if (tid < 128) {
      int bb = tid >> 5, cc = tid & 31;
      float g = red[0][bb][cc] + red[1][bb][cc] + red[2][bb][cc] + red[3][bb][cc] +
                red[4][bb][cc] + red[5][bb][cc] + red[6][bb][cc] + red[7][bb][cc];
      int gg = cc >> 3, hh = cc & 7;
      int uc = gg * HD + p * 8 + hh;
      float xv;
      if (!isA && tokB) {
        int token = tokB[bb * lenB + t];
        xv = xg[(size_t)token * G4 + uc];
      } else {
        xv = xg[((size_t)bb * len + t) * G4 + uc];
      }
      gl[bb][cc] = g + xv;
    }
    __syncthreads();

    if (tid < 32) {
      int bb = tid >> 3, hh = tid & 7;
      float gi = gl[bb][hh], gf = gl[bb][8 + hh], gc = gl[bb][16 + hh], go = gl[bb][24 + hh];
      float si = 1.0f / (1.0f + expf(-gi));
      float sf = 1.0f / (1.0f + expf(-gf));
      float so = 1.0f / (1.0f + expf(-go));
      float cN = sf * cst[bb][hh] + si * tanhf(gc);
      float hN = so * tanhf(cN);
      cst[bb][hh] = cN;
      int hidx = p * 8 + hh;
      // write-through to LLC; no fence needed
      __hip_atomic_store(&hbuf[(par ^ 1) * (NB * HD) + bb * HD + hidx], hN,
                         __ATOMIC_RELAXED, __HIP_MEMORY_SCOPE_AGENT);
      hseq[((size_t)bb * len + t) * HD + hidx] = hN;   // consumed by later kernels
      if (isA && finalA && t == len - 1) {
        finalA[bb * HD + hidx] = hN;
        finalA[NB * HD + bb * HD + hidx] = cN;
      }
    }
    __syncthreads();   // compiler drains vmcnt before s_barrier -> h stores retired

    if (t + 1 < len) {
      asm volatile("s_waitcnt vmcnt(0)" ::: "memory");  // belt-and-braces ordering
      if (tid == 0)
        __hip_atomic_store(&flags[p * 32], (unsigned)(t + 1),
                           __ATOMIC_RELAXED, __HIP_MEMORY_SCOPE_AGENT);
      if (tid < 128) {
        while (__hip_atomic_load(&flags[tid * 32], __ATOMIC_RELAXED,
                                 __HIP_MEMORY_SCOPE_AGENT) < (unsigned)(t + 1)) {
          __builtin_amdgcn_s_sleep(1);
        }
      }
      __syncthreads();
      // no acquire fence: next-step h reads are cache-bypassing (LLC-fresh)
    }
  }
}

// -------- fused softmax + s@Wp + bp. One block per (b,t); 64u x 64v output tile.
__global__ __launch_bounds__(256) void final_kernel(
    const float* __restrict__ xsA, const float* __restrict__ psA,
    const float* __restrict__ csA, const float* __restrict__ Wp,
    const float* __restrict__ bp, float* __restrict__ out) {
  __shared__ float xc[SMAXD];       // 16KB
  __shared__ float el[64][68];      // 17.4KB  e[k][u]
  __shared__ float wl[64][68];      // 17.4KB  Wp[k][v]
  __shared__ float Dl[64];
  int bt = blockIdx.x;
  int b = bt >> 7, t = bt & 127;
  int tid = threadIdx.x;
  int tx = tid & 15, uy = tid >> 4;
  for (int i = tid; i < SMAXD; i += 256) xc[i] = xsA[(size_t)bt * SMAXD + i] + csA[i];
  const float* psrow = psA + (size_t)b * UU * SMAXD;
  float acc[4][4] = {};
  float d0 = 0.f, d1 = 0.f, d2 = 0.f, d3 = 0.f;
  for (int k0 = 0; k0 < SMAXD; k0 += 64) {
    __syncthreads();
#pragma unroll
    for (int i = 0; i < 16; ++i) {
      int idx = tid + i * 256;
      int kl = idx >> 6, vl = idx & 63;
      wl[kl][vl] = Wp[(size_t)(k0 + kl) * NV + vl];
    }
#pragma unroll
    for (int i = 0; i < 16; ++i) {
      int idx = tid + i * 256;
      int u = idx >> 6, kl = idx & 63;
      float l = xc[k0 + kl] + psrow[(size_t)u * SMAXD + k0 + kl];
      el[kl][u] = __expf(l);   // logits are tiny; shared-shift softmax needs no max pass
    }
    __syncthreads();
#pragma unroll 4
    for (int k = 0; k < 64; ++k) {
      float4 e4 = *(const float4*)&el[k][uy * 4];
      float4 w4 = *(const float4*)&wl[k][tx * 4];
      d0 += e4.x; d1 += e4.y; d2 += e4.z; d3 += e4.w;
      acc[0][0] = fmaf(e4.x, w4.x, acc[0][0]);
      acc[0][1] = fmaf(e4.x, w4.y, acc[0][1]);
      acc[0][2] = fmaf(e4.x, w4.z, acc[0][2]);
      acc[0][3] = fmaf(e4.x, w4.w, acc[0][3]);
      acc[1][0] = fmaf(e4.y, w4.x, acc[1][0]);
      acc[1][1] = fmaf(e4.y, w4.y, acc[1][1]);
      acc[1][2] = fmaf(e4.y, w4.z, acc[1][2]);
      acc[1][3] = fmaf(e4.y, w4.w, acc[1][3]);
      acc[2][0] = fmaf(e4.z, w4.x, acc[2][0]);
      acc[2][1] = fmaf(e4.z, w4.y, acc[2][1]);
      acc[2][2] = fmaf(e4.z, w4.z, acc[2][2]);
      acc[2][3] = fmaf(e4.z, w4.w, acc[2][3]);
      acc[3][0] = fmaf(e4.w, w4.x, acc[3][0]);
      acc[3][1] = fmaf(e4.w, w4.y, acc[3][1]);
      acc[3][2] = fmaf(e4.w, w4.z, acc[3][2]);
      acc[3][3] = fmaf(e4.w, w4.w, acc[3][3]);
    }
  }
  if (tx == 0) {
    Dl[uy * 4 + 0] = d0; Dl[uy * 4 + 1] = d1;
    Dl[uy * 4 + 2] = d2; Dl[uy * 4 + 3] = d3;
  }
  __syncthreads();
#pragma unroll
  for (int j = 0; j < 4; ++j) {
    int u = uy * 4 + j;
    float dinv = 1.0f / Dl[u];
    float4 o;
    o.x = fmaf(acc[j][0], dinv, bp[tx * 4 + 0]);
    o.y = fmaf(acc[j][1], dinv, bp[tx * 4 + 1]);
    o.z = fmaf(acc[j][2], dinv, bp[tx * 4 + 2]);
    o.w = fmaf(acc[j][3], dinv, bp[tx * 4 + 3]);
    *(float4*)&out[(((size_t)(b * TT + t) * UU + u) * NV) + tx * 4] = o;
  }
}

extern "C" void kernel_launch(void* const* d_in, const int* in_sizes, int n_in,
                              void* d_out, int out_size, void* d_ws, size_t ws_size,
                              hipStream_t stream) {
  (void)in_sizes; (void)n_in; (void)out_size; (void)ws_size;
  const float* encoder_inp   = (const float*)d_in[0];
  const int*   pred_inp      = (const int*)d_in[1];
  const float* encoder_state = (const float*)d_in[2];
  const float* enc_W0 = (const float*)d_in[3];
  const float* enc_U0 = (const float*)d_in[4];
  const float* enc_b0 = (const float*)d_in[5];
  const float* enc_W1 = (const float*)d_in[6];
  const float* enc_U1 = (const float*)d_in[7];
  const float* enc_b1 = (const float*)d_in[8];
  const float* embed   = (const float*)d_in[9];
  const float* pred_W0 = (const float*)d_in[10];
  const float* pred_U0 = (const float*)d_in[11];
  const float* pred_b0 = (const float*)d_in[12];
  const float* pred_W1 = (const float*)d_in[13];
  const float* pred_U1 = (const float*)d_in[14];
  const float* pred_b1 = (const float*)d_in[15];
  const float* Wj = (const float*)d_in[16];
  const float* bj = (const float*)d_in[17];
  const float* Ws = (const float*)d_in[18];
  const float* bs = (const float*)d_in[19];
  const float* Wp = (const float*)d_in[20];
  const float* bp = (const float*)d_in[21];
  float* outp = (float*)d_out;

  char* wsb = (char*)d_ws;
  size_t off = 0;
  auto alloc = [&](size_t bytes) -> void* {
    void* p = (void*)(wsb + off);
    off += (bytes + 255) & ~(size_t)255;
    return p;
  };
  float*    Ut_e0 = (float*)alloc((size_t)G4 * HD * 4);
  float*    Ut_e1 = (float*)alloc((size_t)G4 * HD * 4);
  ushort_t* Ut_p0 = (ushort_t*)alloc((size_t)G4 * HD * 2);
  ushort_t* Ut_p1 = (ushort_t*)alloc((size_t)G4 * HD * 2);
  float* xg_e0 = (float*)alloc((size_t)NB * TT * G4 * 4);
  float* ptab  = (float*)alloc((size_t)NV * G4 * 4);
  float* xg_e1 = (float*)alloc((size_t)NB * TT * G4 * 4);
  float* xg_p1 = (float*)alloc((size_t)NB * UU * G4 * 4);
  float* h0s  = (float*)alloc((size_t)NB * TT * HD * 4);
  float* hp0s = (float*)alloc((size_t)NB * UU * HD * 4);
  float* h1s  = (float*)alloc((size_t)NB * TT * HD * 4);
  float* hp1s = (float*)alloc((size_t)NB * UU * HD * 4);
  float* xjb = (float*)alloc((size_t)NB * TT * JD * 4);
  float* pjb = (float*)alloc((size_t)NB * UU * JD * 4);
  float* xsb = (float*)alloc((size_t)NB * TT * SMAXD * 4);
  float* psb = (float*)alloc((size_t)NB * UU * SMAXD * 4);
  float* csb = (float*)alloc((size_t)SMAXD * 4);
  float* hbufs = (float*)alloc((size_t)4 * 2 * NB * HD * 4);
  unsigned int* bars = (unsigned int*)alloc((size_t)4 * 128 * 32 * 4);  // 4 groups of 128 padded flags

  float* hbufA_enc  = hbufs;
  float* hbufA_pred = hbufs + 2 * NB * HD;
  float* hbufC_enc  = hbufs + 4 * NB * HD;
  float* hbufC_pred = hbufs + 6 * NB * HD;

  unsigned int* flags_e0 = bars;
  unsigned int* flags_p0 = bars + 1 * 128 * 32;
  unsigned int* flags_e1 = bars + 2 * 128 * 32;
  unsigned int* flags_p1 = bars + 3 * 128 * 32;

  hipMemsetAsync(hbufs, 0, (size_t)4 * 2 * NB * HD * 4, stream);
  hipMemsetAsync(bars, 0, (size_t)4 * 128 * 32 * 4, stream);
  hipMemcpyAsync(hbufA_enc, encoder_state, (size_t)NB * HD * 4, hipMemcpyDeviceToDevice, stream);
  hipMemcpyAsync(hbufC_enc, encoder_state, (size_t)NB * HD * 4, hipMemcpyDeviceToDevice, stream);

  dim3 tb(32, 8);
  transpose_f32 <<<dim3(G4 / 32, HD / 32), tb, 0, stream>>>(enc_U0, Ut_e0, HD, G4);
  transpose_f32 <<<dim3(G4 / 32, HD / 32), tb, 0, stream>>>(enc_U1, Ut_e1, HD, G4);
  transpose_bf16<<<dim3(G4 / 32, HD / 32), tb, 0, stream>>>(pred_U0, Ut_p0, HD, G4);
  transpose_bf16<<<dim3(G4 / 32, HD / 32), tb, 0, stream>>>(pred_U1, Ut_p1, HD, G4);

  inproj_kernel<<<NB * TT, 256, 0, stream>>>(encoder_inp, enc_W0, enc_b0, xg_e0, NFEAT);
  inproj_kernel<<<NV, 256, 0, stream>>>(embed, pred_W0, pred_b0, ptab, 64);

  // phase 1: enc0 (blocks 0..127) || pred0 (blocks 128..255)
  lstm_kernel<<<256, 256, 0, stream>>>(
      xg_e0, TT, Ut_e0, encoder_state + NB * HD, h0s, hbufA_enc, nullptr,
      ptab, UU, pred_inp, Ut_p0, hp0s, hbufA_pred, flags_e0, flags_p0);

  // layer-1 input projections (batched)
  gemm_kernel<<<dim3(G4 / 64, (NB * TT) / 64), 256, 0, stream>>>(h0s, enc_W1, enc_b1, xg_e1, NB * TT, G4, HD);
  gemm_kernel<<<dim3(G4 / 64, (NB * UU) / 64), 256, 0, stream>>>(hp0s, pred_W1, pred_b1, xg_p1, NB * UU, G4, HD);

  // phase 2: enc1 || pred1 ; enc1 writes final state to d_out tail
  lstm_kernel<<<256, 256, 0, stream>>>(
      xg_e1, TT, Ut_e1, encoder_state + NB * HD, h1s, hbufC_enc,
      outp + (size_t)NB * TT * UU * NV,
      xg_p1, UU, nullptr, Ut_p1, hp1s, hbufC_pred, flags_e1, flags_p1);

  // factored joint: xs = (x@Wj)@Ws ; ps = (p@Wj)@Ws ; cs = bj@Ws + bs
  gemm_kernel<<<dim3(JD / 64, (NB * TT) / 64), 256, 0, stream>>>(h1s, Wj, nullptr, xjb, NB * TT, JD, HD);
  gemm_kernel<<<dim3(JD / 64, (NB * UU) / 64), 256, 0, stream>>>(hp1s, Wj, nullptr, pjb, NB * UU, JD, HD);
  gemm_kernel<<<dim3(SMAXD / 64, (NB * TT) / 64), 256, 0, stream>>>(xjb, Ws, nullptr, xsb, NB * TT, SMAXD, JD);
  gemm_kernel<<<dim3(SMAXD / 64, (NB * UU) / 64), 256, 0, stream>>>(pjb, Ws, nullptr, psb, NB * UU, SMAXD, JD);
  cs_kernel<<<SMAXD / 256, 256, 0, stream>>>(bj, Ws, bs, csb);

  final_kernel<<<NB * TT, 256, 0, stream>>>(xsb, psb, csb, Wp, bp, outp);
}

// Round 9
// 2820.399 us; speedup vs baseline: 2.4525x; 1.3102x over previous
//
#include <hip/hip_runtime.h>
#include <stdint.h>

typedef unsigned short ushort_t;

#define HD 1024
#define G4 4096
#define NB 4
#define TT 128
#define UU 64
#define NFEAT 80
#define SMAXD 4096
#define JD 640
#define NV 64

static __device__ __forceinline__ float lo2f(uint32_t u) {
  union { uint32_t i; float f; } v; v.i = u << 16; return v.f;
}
static __device__ __forceinline__ float hi2f(uint32_t u) {
  union { uint32_t i; float f; } v; v.i = u & 0xffff0000u; return v.f;
}
static __device__ __forceinline__ ushort_t f2bf(float f) {
  union { uint32_t i; float f; } v; v.f = f;
  return (ushort_t)((v.i + 0x7fffu + ((v.i >> 16) & 1u)) >> 16);
}

// ---------------- transpose: src [K,N] f32 -> dst [N,K] ----------------
__global__ void transpose_f32(const float* __restrict__ src, float* __restrict__ dst,
                              int K, int N) {
  __shared__ float tile[32][33];
  int n0 = blockIdx.x * 32, k0 = blockIdx.y * 32;
  int tx = threadIdx.x, ty = threadIdx.y;
#pragma unroll
  for (int j = 0; j < 32; j += 8)
    tile[ty + j][tx] = src[(size_t)(k0 + ty + j) * N + n0 + tx];
  __syncthreads();
#pragma unroll
  for (int j = 0; j < 32; j += 8)
    dst[(size_t)(n0 + ty + j) * K + k0 + tx] = tile[tx][ty + j];
}

__global__ void transpose_bf16(const float* __restrict__ src, ushort_t* __restrict__ dst,
                               int K, int N) {
  __shared__ float tile[32][33];
  int n0 = blockIdx.x * 32, k0 = blockIdx.y * 32;
  int tx = threadIdx.x, ty = threadIdx.y;
#pragma unroll
  for (int j = 0; j < 32; j += 8)
    tile[ty + j][tx] = src[(size_t)(k0 + ty + j) * N + n0 + tx];
  __syncthreads();
#pragma unroll
  for (int j = 0; j < 32; j += 8)
    dst[(size_t)(n0 + ty + j) * K + k0 + tx] = f2bf(tile[tx][ty + j]);
}

// -------- input projection: C[m,:] = X[m,:K] @ W[K,4096] + bias (one block per row m)
__global__ __launch_bounds__(256) void inproj_kernel(
    const float* __restrict__ X, const float* __restrict__ W,
    const float* __restrict__ bias, float* __restrict__ C, int K) {
  __shared__ float xls[JD];
  int m = blockIdx.x;
  int tid = threadIdx.x;
  for (int i = tid; i < K; i += 256) xls[i] = X[(size_t)m * K + i];
  __syncthreads();
  for (int c = tid; c < G4; c += 256) {
    float acc = bias[c];
    for (int k = 0; k < K; ++k) acc = fmaf(xls[k], W[(size_t)k * G4 + c], acc);
    C[(size_t)m * G4 + c] = acc;
  }
}

// -------- cs[c] = bs[c] + sum_k bj[k] * Ws[k,c] ; grid 16 x 256
__global__ __launch_bounds__(256) void cs_kernel(const float* __restrict__ bj,
                                                 const float* __restrict__ Ws,
                                                 const float* __restrict__ bs,
                                                 float* __restrict__ cs) {
  __shared__ float bl[JD];
  int tid = threadIdx.x;
  for (int i = tid; i < JD; i += 256) bl[i] = bj[i];
  __syncthreads();
  int c = blockIdx.x * 256 + tid;
  float acc = bs[c];
  for (int k = 0; k < JD; ++k) acc = fmaf(bl[k], Ws[(size_t)k * G4 + c], acc);
  cs[c] = acc;
}

// -------- generic GEMM: C[M,N] = A[M,K] @ B[K,N] (+ bias over N). 64x64 tile, BK=32.
__global__ __launch_bounds__(256) void gemm_kernel(
    const float* __restrict__ A, const float* __restrict__ Bm,
    const float* __restrict__ bias, float* __restrict__ C,
    int M, int N, int K) {
  __shared__ float As[32][68];
  __shared__ float Bs[32][68];
  int n0 = blockIdx.x * 64, m0 = blockIdx.y * 64;
  int tid = threadIdx.x;
  int tx = tid & 15, ty = tid >> 4;
  float acc[4][4] = {};
  for (int k0 = 0; k0 < K; k0 += 32) {
#pragma unroll
    for (int i = 0; i < 8; ++i) {
      int idx = tid + i * 256;
      int ml = idx >> 5, kl = idx & 31;
      As[kl][ml] = A[(size_t)(m0 + ml) * K + k0 + kl];
      int kl2 = idx >> 6, nl = idx & 63;
      Bs[kl2][nl] = Bm[(size_t)(k0 + kl2) * N + n0 + nl];
    }
    __syncthreads();
#pragma unroll 8
    for (int k = 0; k < 32; ++k) {
      float4 a4 = *(const float4*)&As[k][ty * 4];
      float4 b4 = *(const float4*)&Bs[k][tx * 4];
      acc[0][0] = fmaf(a4.x, b4.x, acc[0][0]);
      acc[0][1] = fmaf(a4.x, b4.y, acc[0][1]);
      acc[0][2] = fmaf(a4.x, b4.z, acc[0][2]);
      acc[0][3] = fmaf(a4.x, b4.w, acc[0][3]);
      acc[1][0] = fmaf(a4.y, b4.x, acc[1][0]);
      acc[1][1] = fmaf(a4.y, b4.y, acc[1][1]);
      acc[1][2] = fmaf(a4.y, b4.z, acc[1][2]);
      acc[1][3] = fmaf(a4.y, b4.w, acc[1][3]);
      acc[2][0] = fmaf(a4.z, b4.x, acc[2][0]);
      acc[2][1] = fmaf(a4.z, b4.y, acc[2][1]);
      acc[2][2] = fmaf(a4.z, b4.z, acc[2][2]);
      acc[2][3] = fmaf(a4.z, b4.w, acc[2][3]);
      acc[3][0] = fmaf(a4.w, b4.x, acc[3][0]);
      acc[3][1] = fmaf(a4.w, b4.y, acc[3][1]);
      acc[3][2] = fmaf(a4.w, b4.z, acc[3][2]);
      acc[3][3] = fmaf(a4.w, b4.w, acc[3][3]);
    }
    __syncthreads();
  }
  float b0 = 0.f, b1 = 0.f, b2 = 0.f, b3 = 0.f;
  if (bias) {
    b0 = bias[n0 + tx * 4 + 0]; b1 = bias[n0 + tx * 4 + 1];
    b2 = bias[n0 + tx * 4 + 2]; b3 = bias[n0 + tx * 4 + 3];
  }
#pragma unroll
  for (int i = 0; i < 4; ++i) {
    float4 o;
    o.x = acc[i][0] + b0; o.y = acc[i][1] + b1; o.z = acc[i][2] + b2; o.w = acc[i][3] + b3;
    *(float4*)&C[(size_t)(m0 + ty * 4 + i) * N + n0 + tx * 4] = o;
  }
}

// -------- persistent dual-layer LSTM stepper, 256 blocks x 256 threads.
// blocks [0,128): group A (encoder, U fp32); blocks [128,256): group B (pred, U bf16).
// Cross-block h exchange via LLC (cache-bypass sc0 sc1), relaxed ordering only:
// h-stores retired via vmcnt(0) before the flag-store; gather uses WIDE
// global_load_dwordx4 sc0 sc1 (4x fewer LLC transactions than dword atomics).
// Thread tid owns the contiguous 64B [tid*64, tid*64+64) of hbuf.
__global__ __launch_bounds__(256, 1) void lstm_kernel(
    const float* __restrict__ xgA, int lenA,
    const float* __restrict__ UtA,     // [4096][1024] f32 (transposed)
    const float* __restrict__ cinitA,  // [4*1024] or nullptr
    float* __restrict__ hseqA,         // [4, lenA, 1024]
    float* __restrict__ hbufA,         // [2][4*1024]
    float* __restrict__ finalA,        // nullptr or [2][4][1024] (h then c)
    const float* __restrict__ xgB, int lenB,  // table [64,4096] if tokB else [4,lenB,4096]
    const int* __restrict__ tokB,
    const ushort_t* __restrict__ UtB,  // [4096][1024] bf16 (transposed)
    float* __restrict__ hseqB,
    float* __restrict__ hbufB,
    unsigned int* __restrict__ flagsA,
    unsigned int* __restrict__ flagsB) {
  __shared__ float hprev[NB][HD];     // 16KB
  __shared__ float red[8][NB][32];    // 4KB
  __shared__ float gl[NB][32];
  __shared__ float cst[NB][8];
  int blk = blockIdx.x;
  int isA = (blk < 128) ? 1 : 0;
  int p = blk & 127;
  int tid = threadIdx.x;
  int c = tid & 31, s = tid >> 5;     // col-local, k-slice
  int len = isA ? lenA : lenB;
  const float* xg = isA ? xgA : xgB;
  float* hseq = isA ? hseqA : hseqB;
  float* hbuf = isA ? hbufA : hbufB;
  unsigned int* flags = isA ? flagsA : flagsB;

  if (tid < 32) {
    int bb = tid >> 3, hh = tid & 7;
    cst[bb][hh] = (isA && cinitA) ? cinitA[bb * HD + p * 8 + hh] : 0.0f;
  }

  int gate = c >> 3, hic = c & 7;
  int ucol = gate * HD + p * 8 + hic;
  int kb = s * 128;

  // ---- hoist this thread's U slice (128 floats) into registers ----
  float u[128];
  if (isA) {
    const float4* ur = (const float4*)(UtA + (size_t)ucol * HD + kb);
#pragma unroll
    for (int i = 0; i < 32; ++i) ((float4*)u)[i] = ur[i];
  } else {
    const uint4* ur = (const uint4*)(UtB + (size_t)ucol * HD + kb);
#pragma unroll
    for (int i = 0; i < 16; ++i) {
      uint4 q = ur[i];
      u[i * 8 + 0] = lo2f(q.x); u[i * 8 + 1] = hi2f(q.x);
      u[i * 8 + 2] = lo2f(q.y); u[i * 8 + 3] = hi2f(q.y);
      u[i * 8 + 4] = lo2f(q.z); u[i * 8 + 5] = hi2f(q.z);
      u[i * 8 + 6] = lo2f(q.w); u[i * 8 + 7] = hi2f(q.w);
    }
  }

  for (int t = 0; t < len; ++t) {
    int par = t & 1;
    const float* hsrc = hbuf + par * (NB * HD);
    // gather fresh h from LLC: 4x global_load_dwordx4 sc0 sc1 (cache-bypass),
    // one vmcnt drain for all four. Thread tid reads bytes [tid*64, tid*64+64).
    {
      const float* pb = hsrc + tid * 16;
      float4 r0, r1, r2, r3;
      asm volatile(
          "global_load_dwordx4 %0, %4, off sc0 sc1\n\t"
          "global_load_dwordx4 %1, %4, off offset:16 sc0 sc1\n\t"
          "global_load_dwordx4 %2, %4, off offset:32 sc0 sc1\n\t"
          "global_load_dwordx4 %3, %4, off offset:48 sc0 sc1\n\t"
          "s_waitcnt vmcnt(0)"
          : "=&v"(r0), "=&v"(r1), "=&v"(r2), "=&v"(r3)
          : "v"(pb)
          : "memory");
      float4* hp4 = (float4*)&hprev[0][0];
      hp4[tid * 4 + 0] = r0;
      hp4[tid * 4 + 1] = r1;
      hp4[tid * 4 + 2] = r2;
      hp4[tid * 4 + 3] = r3;
    }
    __syncthreads();

    float aa[4] = {0.f, 0.f, 0.f, 0.f};
#pragma unroll
    for (int k4 = 0; k4 < 32; ++k4) {
#pragma unroll
      for (int bb = 0; bb < 4; ++bb) {
        float4 h4 = *(const float4*)&hprev[bb][kb + k4 * 4];
        aa[bb] = fmaf(u[k4 * 4 + 0], h4.x, aa[bb]);
        aa[bb] = fmaf(u[k4 * 4 + 1], h4.y, aa[bb]);
        aa[bb] = fmaf(u[k4 * 4 + 2], h4.z, aa[bb]);
        aa[bb] = fmaf(u[k4 * 4 + 3], h4.w, aa[bb]);
      }
    }
    red[s][0][c] = aa[0]; red[s][1][c] = aa[1];
    red[s][2][c] = aa[2]; red[s][3][c] = aa[3];
    __syncthreads();

    if (tid < 128) {
      int bb = tid >> 5, cc = tid & 31;
      float g = red[0][bb][cc] + red[1][bb][cc] + red[2][bb][cc] + red[3][bb][cc] +
                red[4][bb][cc] + red[5][bb][cc] + red[6][bb][cc] + red[7][bb][cc];
      int gg = cc >> 3, hh = cc & 7;
      int uc = gg * HD + p * 8 + hh;
      float xv;
      if (!isA && tokB) {
        int token = tokB[bb * lenB + t];
        xv = xg[(size_t)token * G4 + uc];
      } else {
        xv = xg[((size_t)bb * len + t) * G4 + uc];
      }
      gl[bb][cc] = g + xv;
    }
    __syncthreads();

    if (tid < 32) {
      int bb = tid >> 3, hh = tid & 7;
      float gi = gl[bb][hh], gf = gl[bb][8 + hh], gc = gl[bb][16 + hh], go = gl[bb][24 + hh];
      float si = 1.0f / (1.0f + expf(-gi));
      float sf = 1.0f / (1.0f + expf(-gf));
      float so = 1.0f / (1.0f + expf(-go));
      float cN = sf * cst[bb][hh] + si * tanhf(gc);
      float hN = so * tanhf(cN);
      cst[bb][hh] = cN;
      int hidx = p * 8 + hh;
      // write-through to LLC; no fence needed
      __hip_atomic_store(&hbuf[(par ^ 1) * (NB * HD) + bb * HD + hidx], hN,
                         __ATOMIC_RELAXED, __HIP_MEMORY_SCOPE_AGENT);
      hseq[((size_t)bb * len + t) * HD + hidx] = hN;   // consumed by later kernels
      if (isA && finalA && t == len - 1) {
        finalA[bb * HD + hidx] = hN;
        finalA[NB * HD + bb * HD + hidx] = cN;
      }
    }
    __syncthreads();   // compiler drains vmcnt before s_barrier -> h stores retired

    if (t + 1 < len) {
      asm volatile("s_waitcnt vmcnt(0)" ::: "memory");  // h stores retired before flag
      if (tid == 0)
        __hip_atomic_store(&flags[p * 32], (unsigned)(t + 1),
                           __ATOMIC_RELAXED, __HIP_MEMORY_SCOPE_AGENT);
      if (tid < 128) {
        while (__hip_atomic_load(&flags[tid * 32], __ATOMIC_RELAXED,
                                 __HIP_MEMORY_SCOPE_AGENT) < (unsigned)(t + 1)) {
          __builtin_amdgcn_s_sleep(4);   // backoff: cut LLC poll traffic
        }
      }
      __syncthreads();
      // no acquire fence: next-step h reads are cache-bypassing (LLC-fresh)
    }
  }
}

// -------- fused softmax + s@Wp + bp. One block per (b,t); 64u x 64v output tile.
__global__ __launch_bounds__(256) void final_kernel(
    const float* __restrict__ xsA, const float* __restrict__ psA,
    const float* __restrict__ csA, const float* __restrict__ Wp,
    const float* __restrict__ bp, float* __restrict__ out) {
  __shared__ float xc[SMAXD];       // 16KB
  __shared__ float el[64][68];      // 17.4KB  e[k][u]
  __shared__ float wl[64][68];      // 17.4KB  Wp[k][v]
  __shared__ float Dl[64];
  int bt = blockIdx.x;
  int b = bt >> 7, t = bt & 127;
  int tid = threadIdx.x;
  int tx = tid & 15, uy = tid >> 4;
  for (int i = tid; i < SMAXD; i += 256) xc[i] = xsA[(size_t)bt * SMAXD + i] + csA[i];
  const float* psrow = psA + (size_t)b * UU * SMAXD;
  float acc[4][4] = {};
  float d0 = 0.f, d1 = 0.f, d2 = 0.f, d3 = 0.f;
  for (int k0 = 0; k0 < SMAXD; k0 += 64) {
    __syncthreads();
#pragma unroll
    for (int i = 0; i < 16; ++i) {
      int idx = tid + i * 256;
      int kl = idx >> 6, vl = idx & 63;
      wl[kl][vl] = Wp[(size_t)(k0 + kl) * NV + vl];
    }
#pragma unroll
    for (int i = 0; i < 16; ++i) {
      int idx = tid + i * 256;
      int u = idx >> 6, kl = idx & 63;
      float l = xc[k0 + kl] + psrow[(size_t)u * SMAXD + k0 + kl];
      el[kl][u] = __expf(l);   // logits are tiny; shared-shift softmax needs no max pass
    }
    __syncthreads();
#pragma unroll 4
    for (int k = 0; k < 64; ++k) {
      float4 e4 = *(const float4*)&el[k][uy * 4];
      float4 w4 = *(const float4*)&wl[k][tx * 4];
      d0 += e4.x; d1 += e4.y; d2 += e4.z; d3 += e4.w;
      acc[0][0] = fmaf(e4.x, w4.x, acc[0][0]);
      acc[0][1] = fmaf(e4.x, w4.y, acc[0][1]);
      acc[0][2] = fmaf(e4.x, w4.z, acc[0][2]);
      acc[0][3] = fmaf(e4.x, w4.w, acc[0][3]);
      acc[1][0] = fmaf(e4.y, w4.x, acc[1][0]);
      acc[1][1] = fmaf(e4.y, w4.y, acc[1][1]);
      acc[1][2] = fmaf(e4.y, w4.z, acc[1][2]);
      acc[1][3] = fmaf(e4.y, w4.w, acc[1][3]);
      acc[2][0] = fmaf(e4.z, w4.x, acc[2][0]);
      acc[2][1] = fmaf(e4.z, w4.y, acc[2][1]);
      acc[2][2] = fmaf(e4.z, w4.z, acc[2][2]);
      acc[2][3] = fmaf(e4.z, w4.w, acc[2][3]);
      acc[3][0] = fmaf(e4.w, w4.x, acc[3][0]);
      acc[3][1] = fmaf(e4.w, w4.y, acc[3][1]);
      acc[3][2] = fmaf(e4.w, w4.z, acc[3][2]);
      acc[3][3] = fmaf(e4.w, w4.w, acc[3][3]);
    }
  }
  if (tx == 0) {
    Dl[uy * 4 + 0] = d0; Dl[uy * 4 + 1] = d1;
    Dl[uy * 4 + 2] = d2; Dl[uy * 4 + 3] = d3;
  }
  __syncthreads();
#pragma unroll
  for (int j = 0; j < 4; ++j) {
    int u = uy * 4 + j;
    float dinv = 1.0f / Dl[u];
    float4 o;
    o.x = fmaf(acc[j][0], dinv, bp[tx * 4 + 0]);
    o.y = fmaf(acc[j][1], dinv, bp[tx * 4 + 1]);
    o.z = fmaf(acc[j][2], dinv, bp[tx * 4 + 2]);
    o.w = fmaf(acc[j][3], dinv, bp[tx * 4 + 3]);
    *(float4*)&out[(((size_t)(b * TT + t) * UU + u) * NV) + tx * 4] = o;
  }
}

extern "C" void kernel_launch(void* const* d_in, const int* in_sizes, int n_in,
                              void* d_out, int out_size, void* d_ws, size_t ws_size,
                              hipStream_t stream) {
  (void)in_sizes; (void)n_in; (void)out_size; (void)ws_size;
  const float* encoder_inp   = (const float*)d_in[0];
  const int*   pred_inp      = (const int*)d_in[1];
  const float* encoder_state = (const float*)d_in[2];
  const float* enc_W0 = (const float*)d_in[3];
  const float* enc_U0 = (const float*)d_in[4];
  const float* enc_b0 = (const float*)d_in[5];
  const float* enc_W1 = (const float*)d_in[6];
  const float* enc_U1 = (const float*)d_in[7];
  const float* enc_b1 = (const float*)d_in[8];
  const float* embed   = (const float*)d_in[9];
  const float* pred_W0 = (const float*)d_in[10];
  const float* pred_U0 = (const float*)d_in[11];
  const float* pred_b0 = (const float*)d_in[12];
  const float* pred_W1 = (const float*)d_in[13];
  const float* pred_U1 = (const float*)d_in[14];
  const float* pred_b1 = (const float*)d_in[15];
  const float* Wj = (const float*)d_in[16];
  const float* bj = (const float*)d_in[17];
  const float* Ws = (const float*)d_in[18];
  const float* bs = (const float*)d_in[19];
  const float* Wp = (const float*)d_in[20];
  const float* bp = (const float*)d_in[21];
  float* outp = (float*)d_out;

  char* wsb = (char*)d_ws;
  size_t off = 0;
  auto alloc = [&](size_t bytes) -> void* {
    void* p = (void*)(wsb + off);
    off += (bytes + 255) & ~(size_t)255;
    return p;
  };
  float*    Ut_e0 = (float*)alloc((size_t)G4 * HD * 4);
  float*    Ut_e1 = (float*)alloc((size_t)G4 * HD * 4);
  ushort_t* Ut_p0 = (ushort_t*)alloc((size_t)G4 * HD * 2);
  ushort_t* Ut_p1 = (ushort_t*)alloc((size_t)G4 * HD * 2);
  float* xg_e0 = (float*)alloc((size_t)NB * TT * G4 * 4);
  float* ptab  = (float*)alloc((size_t)NV * G4 * 4);
  float* xg_e1 = (float*)alloc((size_t)NB * TT * G4 * 4);
  float* xg_p1 = (float*)alloc((size_t)NB * UU * G4 * 4);
  float* h0s  = (float*)alloc((size_t)NB * TT * HD * 4);
  float* hp0s = (float*)alloc((size_t)NB * UU * HD * 4);
  float* h1s  = (float*)alloc((size_t)NB * TT * HD * 4);
  float* hp1s = (float*)alloc((size_t)NB * UU * HD * 4);
  float* xjb = (float*)alloc((size_t)NB * TT * JD * 4);
  float* pjb = (float*)alloc((size_t)NB * UU * JD * 4);
  float* xsb = (float*)alloc((size_t)NB * TT * SMAXD * 4);
  float* psb = (float*)alloc((size_t)NB * UU * SMAXD * 4);
  float* csb = (float*)alloc((size_t)SMAXD * 4);
  float* hbufs = (float*)alloc((size_t)4 * 2 * NB * HD * 4);
  unsigned int* bars = (unsigned int*)alloc((size_t)4 * 128 * 32 * 4);  // 4 groups of 128 padded flags

  float* hbufA_enc  = hbufs;
  float* hbufA_pred = hbufs + 2 * NB * HD;
  float* hbufC_enc  = hbufs + 4 * NB * HD;
  float* hbufC_pred = hbufs + 6 * NB * HD;

  unsigned int* flags_e0 = bars;
  unsigned int* flags_p0 = bars + 1 * 128 * 32;
  unsigned int* flags_e1 = bars + 2 * 128 * 32;
  unsigned int* flags_p1 = bars + 3 * 128 * 32;

  hipMemsetAsync(hbufs, 0, (size_t)4 * 2 * NB * HD * 4, stream);
  hipMemsetAsync(bars, 0, (size_t)4 * 128 * 32 * 4, stream);
  hipMemcpyAsync(hbufA_enc, encoder_state, (size_t)NB * HD * 4, hipMemcpyDeviceToDevice, stream);
  hipMemcpyAsync(hbufC_enc, encoder_state, (size_t)NB * HD * 4, hipMemcpyDeviceToDevice, stream);

  dim3 tb(32, 8);
  transpose_f32 <<<dim3(G4 / 32, HD / 32), tb, 0, stream>>>(enc_U0, Ut_e0, HD, G4);
  transpose_f32 <<<dim3(G4 / 32, HD / 32), tb, 0, stream>>>(enc_U1, Ut_e1, HD, G4);
  transpose_bf16<<<dim3(G4 / 32, HD / 32), tb, 0, stream>>>(pred_U0, Ut_p0, HD, G4);
  transpose_bf16<<<dim3(G4 / 32, HD / 32), tb, 0, stream>>>(pred_U1, Ut_p1, HD, G4);

  inproj_kernel<<<NB * TT, 256, 0, stream>>>(encoder_inp, enc_W0, enc_b0, xg_e0, NFEAT);
  inproj_kernel<<<NV, 256, 0, stream>>>(embed, pred_W0, pred_b0, ptab, 64);

  // phase 1: enc0 (blocks 0..127) || pred0 (blocks 128..255)
  lstm_kernel<<<256, 256, 0, stream>>>(
      xg_e0, TT, Ut_e0, encoder_state + NB * HD, h0s, hbufA_enc, nullptr,
      ptab, UU, pred_inp, Ut_p0, hp0s, hbufA_pred, flags_e0, flags_p0);

  // layer-1 input projections (batched)
  gemm_kernel<<<dim3(G4 / 64, (NB * TT) / 64), 256, 0, stream>>>(h0s, enc_W1, enc_b1, xg_e1, NB * TT, G4, HD);
  gemm_kernel<<<dim3(G4 / 64, (NB * UU) / 64), 256, 0, stream>>>(hp0s, pred_W1, pred_b1, xg_p1, NB * UU, G4, HD);

  // phase 2: enc1 || pred1 ; enc1 writes final state to d_out tail
  lstm_kernel<<<256, 256, 0, stream>>>(
      xg_e1, TT, Ut_e1, encoder_state + NB * HD, h1s, hbufC_enc,
      outp + (size_t)NB * TT * UU * NV,
      xg_p1, UU, nullptr, Ut_p1, hp1s, hbufC_pred, flags_e1, flags_p1);

  // factored joint: xs = (x@Wj)@Ws ; ps = (p@Wj)@Ws ; cs = bj@Ws + bs
  gemm_kernel<<<dim3(JD / 64, (NB * TT) / 64), 256, 0, stream>>>(h1s, Wj, nullptr, xjb, NB * TT, JD, HD);
  gemm_kernel<<<dim3(JD / 64, (NB * UU) / 64), 256, 0, stream>>>(hp1s, Wj, nullptr, pjb, NB * UU, JD, HD);
  gemm_kernel<<<dim3(SMAXD / 64, (NB * TT) / 64), 256, 0, stream>>>(xjb, Ws, nullptr, xsb, NB * TT, SMAXD, JD);
  gemm_kernel<<<dim3(SMAXD / 64, (NB * UU) / 64), 256, 0, stream>>>(pjb, Ws, nullptr, psb, NB * UU, SMAXD, JD);
  cs_kernel<<<SMAXD / 256, 256, 0, stream>>>(bj, Ws, bs, csb);

  final_kernel<<<NB * TT, 256, 0, stream>>>(xsb, psb, csb, Wp, bp, outp);
}

// Round 10
// 2807.577 us; speedup vs baseline: 2.4637x; 1.0046x over previous
//
#include <hip/hip_runtime.h>
#include <stdint.h>

typedef unsigned short ushort_t;

#define HD 1024
#define G4 4096
#define NB 4
#define TT 128
#define UU 64
#define NFEAT 80
#define SMAXD 4096
#define JD 640
#define NV 64
#define CHK 64   // floats per peer chunk: 32 data + tag @32 + pad (256B)

static __device__ __forceinline__ float lo2f(uint32_t u) {
  union { uint32_t i; float f; } v; v.i = u << 16; return v.f;
}
static __device__ __forceinline__ float hi2f(uint32_t u) {
  union { uint32_t i; float f; } v; v.i = u & 0xffff0000u; return v.f;
}
static __device__ __forceinline__ ushort_t f2bf(float f) {
  union { uint32_t i; float f; } v; v.f = f;
  return (ushort_t)((v.i + 0x7fffu + ((v.i >> 16) & 1u)) >> 16);
}

// ---------------- transpose: src [K,N] f32 -> dst [N,K] ----------------
__global__ void transpose_f32(const float* __restrict__ src, float* __restrict__ dst,
                              int K, int N) {
  __shared__ float tile[32][33];
  int n0 = blockIdx.x * 32, k0 = blockIdx.y * 32;
  int tx = threadIdx.x, ty = threadIdx.y;
#pragma unroll
  for (int j = 0; j < 32; j += 8)
    tile[ty + j][tx] = src[(size_t)(k0 + ty + j) * N + n0 + tx];
  __syncthreads();
#pragma unroll
  for (int j = 0; j < 32; j += 8)
    dst[(size_t)(n0 + ty + j) * K + k0 + tx] = tile[tx][ty + j];
}

__global__ void transpose_bf16(const float* __restrict__ src, ushort_t* __restrict__ dst,
                               int K, int N) {
  __shared__ float tile[32][33];
  int n0 = blockIdx.x * 32, k0 = blockIdx.y * 32;
  int tx = threadIdx.x, ty = threadIdx.y;
#pragma unroll
  for (int j = 0; j < 32; j += 8)
    tile[ty + j][tx] = src[(size_t)(k0 + ty + j) * N + n0 + tx];
  __syncthreads();
#pragma unroll
  for (int j = 0; j < 32; j += 8)
    dst[(size_t)(n0 + ty + j) * K + k0 + tx] = f2bf(tile[tx][ty + j]);
}

// -------- init chunk buffers (parity 0) with encoder initial h ----------
// chunk layout: [peer p][bb*8+hh] = h[bb*1024 + p*8 + hh]
__global__ void init_chunks(const float* __restrict__ state_h,
                            float* __restrict__ chunksE0,
                            float* __restrict__ chunksE1) {
  int idx = blockIdx.x * 256 + threadIdx.x;  // 0..4095
  int bb = idx >> 10, rem = idx & 1023;
  int p = rem >> 3, hh = rem & 7;
  float v = state_h[idx];
  chunksE0[p * CHK + bb * 8 + hh] = v;
  chunksE1[p * CHK + bb * 8 + hh] = v;
}

// -------- input projection: C[m,:] = X[m,:K] @ W[K,4096] + bias (one block per row m)
__global__ __launch_bounds__(256) void inproj_kernel(
    const float* __restrict__ X, const float* __restrict__ W,
    const float* __restrict__ bias, float* __restrict__ C, int K) {
  __shared__ float xls[JD];
  int m = blockIdx.x;
  int tid = threadIdx.x;
  for (int i = tid; i < K; i += 256) xls[i] = X[(size_t)m * K + i];
  __syncthreads();
  for (int c = tid; c < G4; c += 256) {
    float acc = bias[c];
    for (int k = 0; k < K; ++k) acc = fmaf(xls[k], W[(size_t)k * G4 + c], acc);
    C[(size_t)m * G4 + c] = acc;
  }
}

// -------- cs[c] = bs[c] + sum_k bj[k] * Ws[k,c] ; grid 16 x 256
__global__ __launch_bounds__(256) void cs_kernel(const float* __restrict__ bj,
                                                 const float* __restrict__ Ws,
                                                 const float* __restrict__ bs,
                                                 float* __restrict__ cs) {
  __shared__ float bl[JD];
  int tid = threadIdx.x;
  for (int i = tid; i < JD; i += 256) bl[i] = bj[i];
  __syncthreads();
  int c = blockIdx.x * 256 + tid;
  float acc = bs[c];
  for (int k = 0; k < JD; ++k) acc = fmaf(bl[k], Ws[(size_t)k * G4 + c], acc);
  cs[c] = acc;
}

// -------- generic GEMM: C[M,N] = A[M,K] @ B[K,N] (+ bias over N). 64x64 tile, BK=32.
__global__ __launch_bounds__(256) void gemm_kernel(
    const float* __restrict__ A, const float* __restrict__ Bm,
    const float* __restrict__ bias, float* __restrict__ C,
    int M, int N, int K) {
  __shared__ float As[32][68];
  __shared__ float Bs[32][68];
  int n0 = blockIdx.x * 64, m0 = blockIdx.y * 64;
  int tid = threadIdx.x;
  int tx = tid & 15, ty = tid >> 4;
  float acc[4][4] = {};
  for (int k0 = 0; k0 < K; k0 += 32) {
#pragma unroll
    for (int i = 0; i < 8; ++i) {
      int idx = tid + i * 256;
      int ml = idx >> 5, kl = idx & 31;
      As[kl][ml] = A[(size_t)(m0 + ml) * K + k0 + kl];
      int kl2 = idx >> 6, nl = idx & 63;
      Bs[kl2][nl] = Bm[(size_t)(k0 + kl2) * N + n0 + nl];
    }
    __syncthreads();
#pragma unroll 8
    for (int k = 0; k < 32; ++k) {
      float4 a4 = *(const float4*)&As[k][ty * 4];
      float4 b4 = *(const float4*)&Bs[k][tx * 4];
      acc[0][0] = fmaf(a4.x, b4.x, acc[0][0]);
      acc[0][1] = fmaf(a4.x, b4.y, acc[0][1]);
      acc[0][2] = fmaf(a4.x, b4.z, acc[0][2]);
      acc[0][3] = fmaf(a4.x, b4.w, acc[0][3]);
      acc[1][0] = fmaf(a4.y, b4.x, acc[1][0]);
      acc[1][1] = fmaf(a4.y, b4.y, acc[1][1]);
      acc[1][2] = fmaf(a4.y, b4.z, acc[1][2]);
      acc[1][3] = fmaf(a4.y, b4.w, acc[1][3]);
      acc[2][0] = fmaf(a4.z, b4.x, acc[2][0]);
      acc[2][1] = fmaf(a4.z, b4.y, acc[2][1]);
      acc[2][2] = fmaf(a4.z, b4.z, acc[2][2]);
      acc[2][3] = fmaf(a4.z, b4.w, acc[2][3]);
      acc[3][0] = fmaf(a4.w, b4.x, acc[3][0]);
      acc[3][1] = fmaf(a4.w, b4.y, acc[3][1]);
      acc[3][2] = fmaf(a4.w, b4.z, acc[3][2]);
      acc[3][3] = fmaf(a4.w, b4.w, acc[3][3]);
    }
    __syncthreads();
  }
  float b0 = 0.f, b1 = 0.f, b2 = 0.f, b3 = 0.f;
  if (bias) {
    b0 = bias[n0 + tx * 4 + 0]; b1 = bias[n0 + tx * 4 + 1];
    b2 = bias[n0 + tx * 4 + 2]; b3 = bias[n0 + tx * 4 + 3];
  }
#pragma unroll
  for (int i = 0; i < 4; ++i) {
    float4 o;
    o.x = acc[i][0] + b0; o.y = acc[i][1] + b1; o.z = acc[i][2] + b2; o.w = acc[i][3] + b3;
    *(float4*)&C[(size_t)(m0 + ty * 4 + i) * N + n0 + tx * 4] = o;
  }
}

// -------- persistent dual-layer LSTM stepper, 256 blocks x 256 threads.
// blocks [0,128): group A (encoder, U fp32); blocks [128,256): group B (pred, U bf16).
// Tag-in-payload exchange: each block owns a 256B chunk [parity][peer][64f]
// (32 h floats + tag word @ float 32). Producer wave stores payload, vmcnt(0),
// then lane0 stores tag=t+1 (same-wave ordering, no fence, no syncthreads).
// Consumer thread-pair (pp=tid>>1) polls its peer's tag >= t, then wide-loads
// 16 floats sc0 sc1 -> LDS. The poll IS the barrier; no separate flag round.
__global__ __launch_bounds__(256, 1) void lstm_kernel(
    const float* __restrict__ xgA, int lenA,
    const float* __restrict__ UtA,     // [4096][1024] f32 (transposed)
    const float* __restrict__ cinitA,  // [4*1024] or nullptr
    float* __restrict__ hseqA,         // [4, lenA, 1024]
    float* __restrict__ chunksA,       // [2][128][CHK]
    float* __restrict__ finalA,        // nullptr or [2][4][1024] (h then c)
    const float* __restrict__ xgB, int lenB,  // table [64,4096] if tokB else [4,lenB,4096]
    const int* __restrict__ tokB,
    const ushort_t* __restrict__ UtB,  // [4096][1024] bf16 (transposed)
    float* __restrict__ hseqB,
    float* __restrict__ chunksB) {
  __shared__ float hprev[NB][HD];     // 16KB
  __shared__ float red[8][NB][32];    // 4KB
  __shared__ float gl[NB][32];
  __shared__ float cst[NB][8];
  int blk = blockIdx.x;
  int isA = (blk < 128) ? 1 : 0;
  int p = blk & 127;
  int tid = threadIdx.x;
  int c = tid & 31, s = tid >> 5;     // col-local, k-slice
  int len = isA ? lenA : lenB;
  const float* xg = isA ? xgA : xgB;
  float* hseq = isA ? hseqA : hseqB;
  float* chunks = isA ? chunksA : chunksB;

  if (tid < 32) {
    int bb = tid >> 3, hh = tid & 7;
    cst[bb][hh] = (isA && cinitA) ? cinitA[bb * HD + p * 8 + hh] : 0.0f;
  }

  int gate = c >> 3, hic = c & 7;
  int ucol = gate * HD + p * 8 + hic;
  int kb = s * 128;

  // ---- hoist this thread's U slice (128 floats) into registers ----
  float u[128];
  if (isA) {
    const float4* ur = (const float4*)(UtA + (size_t)ucol * HD + kb);
#pragma unroll
    for (int i = 0; i < 32; ++i) ((float4*)u)[i] = ur[i];
  } else {
    const uint4* ur = (const uint4*)(UtB + (size_t)ucol * HD + kb);
#pragma unroll
    for (int i = 0; i < 16; ++i) {
      uint4 q = ur[i];
      u[i * 8 + 0] = lo2f(q.x); u[i * 8 + 1] = hi2f(q.x);
      u[i * 8 + 2] = lo2f(q.y); u[i * 8 + 3] = hi2f(q.y);
      u[i * 8 + 4] = lo2f(q.z); u[i * 8 + 5] = hi2f(q.z);
      u[i * 8 + 6] = lo2f(q.w); u[i * 8 + 7] = hi2f(q.w);
    }
  }

  int pp = tid >> 1, half = tid & 1;  // gather role: peer, payload-half

  for (int t = 0; t < len; ++t) {
    int par = t & 1;
    // ---- gather: poll peer tag, wide-load 16 floats, scatter to LDS ----
    {
      const float* chunk = chunks + (size_t)par * (128 * CHK) + pp * CHK;
      const unsigned int* tagp = (const unsigned int*)(chunk + 32);
      while ((int)__hip_atomic_load(tagp, __ATOMIC_RELAXED,
                                    __HIP_MEMORY_SCOPE_AGENT) < t) {
        __builtin_amdgcn_s_sleep(1);
      }
      const float* pb = chunk + half * 16;
      float4 r0, r1, r2, r3;
      asm volatile(
          "global_load_dwordx4 %0, %4, off sc0 sc1\n\t"
          "global_load_dwordx4 %1, %4, off offset:16 sc0 sc1\n\t"
          "global_load_dwordx4 %2, %4, off offset:32 sc0 sc1\n\t"
          "global_load_dwordx4 %3, %4, off offset:48 sc0 sc1\n\t"
          "s_waitcnt vmcnt(0)"
          : "=&v"(r0), "=&v"(r1), "=&v"(r2), "=&v"(r3)
          : "v"(pb)
          : "memory");
      int bb0 = half * 2;                     // floats [half*16, half*16+16) = batches bb0, bb0+1
      float4* d0 = (float4*)&hprev[bb0][pp * 8];
      d0[0] = r0; d0[1] = r1;
      float4* d1 = (float4*)&hprev[bb0 + 1][pp * 8];
      d1[0] = r2; d1[1] = r3;
    }
    __syncthreads();

    float aa[4] = {0.f, 0.f, 0.f, 0.f};
#pragma unroll
    for (int k4 = 0; k4 < 32; ++k4) {
#pragma unroll
      for (int bb = 0; bb < 4; ++bb) {
        float4 h4 = *(const float4*)&hprev[bb][kb + k4 * 4];
        aa[bb] = fmaf(u[k4 * 4 + 0], h4.x, aa[bb]);
        aa[bb] = fmaf(u[k4 * 4 + 1], h4.y, aa[bb]);
        aa[bb] = fmaf(u[k4 * 4 + 2], h4.z, aa[bb]);
        aa[bb] = fmaf(u[k4 * 4 + 3], h4.w, aa[bb]);
      }
    }
    red[s][0][c] = aa[0]; red[s][1][c] = aa[1];
    red[s][2][c] = aa[2]; red[s][3][c] = aa[3];
    __syncthreads();

    if (tid < 128) {
      int bb = tid >> 5, cc = tid & 31;
      float g = red[0][bb][cc] + red[1][bb][cc] + red[2][bb][cc] + red[3][bb][cc] +
                red[4][bb][cc] + red[5][bb][cc] + red[6][bb][cc] + red[7][bb][cc];
      int gg = cc >> 3, hh = cc & 7;
      int uc = gg * HD + p * 8 + hh;
      float xv;
      if (!isA && tokB) {
        int token = tokB[bb * lenB + t];
        xv = xg[(size_t)token * G4 + uc];
      } else {
        xv = xg[((size_t)bb * len + t) * G4 + uc];
      }
      gl[bb][cc] = g + xv;
    }
    __syncthreads();

    if (tid < 32) {
      int bb = tid >> 3, hh = tid & 7;
      float gi = gl[bb][hh], gf = gl[bb][8 + hh], gc = gl[bb][16 + hh], go = gl[bb][24 + hh];
      float si = 1.0f / (1.0f + expf(-gi));
      float sf = 1.0f / (1.0f + expf(-gf));
      float so = 1.0f / (1.0f + expf(-go));
      float cN = sf * cst[bb][hh] + si * tanhf(gc);
      float hN = so * tanhf(cN);
      cst[bb][hh] = cN;
      int hidx = p * 8 + hh;
      float* chunkN = chunks + (size_t)(par ^ 1) * (128 * CHK) + p * CHK;
      // payload store (cache-bypass to LLC)
      __hip_atomic_store(&chunkN[bb * 8 + hh], hN,
                         __ATOMIC_RELAXED, __HIP_MEMORY_SCOPE_AGENT);
      hseq[((size_t)bb * len + t) * HD + hidx] = hN;   // consumed by later kernels
      if (isA && finalA && t == len - 1) {
        finalA[bb * HD + hidx] = hN;
        finalA[NB * HD + bb * HD + hidx] = cN;
      }
      // same-wave ordering: all 32 payload stores retired, then lane0 posts tag
      asm volatile("s_waitcnt vmcnt(0)" ::: "memory");
      if (tid == 0) {
        unsigned int* tagN = (unsigned int*)(chunkN + 32);
        __hip_atomic_store(tagN, (unsigned)(t + 1),
                           __ATOMIC_RELAXED, __HIP_MEMORY_SCOPE_AGENT);
      }
    }
    __syncthreads();
  }
}

// -------- fused softmax + s@Wp + bp. One block per (b,t); 64u x 64v output tile.
__global__ __launch_bounds__(256) void final_kernel(
    const float* __restrict__ xsA, const float* __restrict__ psA,
    const float* __restrict__ csA, const float* __restrict__ Wp,
    const float* __restrict__ bp, float* __restrict__ out) {
  __shared__ float xc[SMAXD];       // 16KB
  __shared__ float el[64][68];      // 17.4KB  e[k][u]
  __shared__ float wl[64][68];      // 17.4KB  Wp[k][v]
  __shared__ float Dl[64];
  int bt = blockIdx.x;
  int b = bt >> 7, t = bt & 127;
  int tid = threadIdx.x;
  int tx = tid & 15, uy = tid >> 4;
  for (int i = tid; i < SMAXD; i += 256) xc[i] = xsA[(size_t)bt * SMAXD + i] + csA[i];
  const float* psrow = psA + (size_t)b * UU * SMAXD;
  float acc[4][4] = {};
  float d0 = 0.f, d1 = 0.f, d2 = 0.f, d3 = 0.f;
  for (int k0 = 0; k0 < SMAXD; k0 += 64) {
    __syncthreads();
#pragma unroll
    for (int i = 0; i < 16; ++i) {
      int idx = tid + i * 256;
      int kl = idx >> 6, vl = idx & 63;
      wl[kl][vl] = Wp[(size_t)(k0 + kl) * NV + vl];
    }
#pragma unroll
    for (int i = 0; i < 16; ++i) {
      int idx = tid + i * 256;
      int u = idx >> 6, kl = idx & 63;
      float l = xc[k0 + kl] + psrow[(size_t)u * SMAXD + k0 + kl];
      el[kl][u] = __expf(l);   // logits are tiny; shared-shift softmax needs no max pass
    }
    __syncthreads();
#pragma unroll 4
    for (int k = 0; k < 64; ++k) {
      float4 e4 = *(const float4*)&el[k][uy * 4];
      float4 w4 = *(const float4*)&wl[k][tx * 4];
      d0 += e4.x; d1 += e4.y; d2 += e4.z; d3 += e4.w;
      acc[0][0] = fmaf(e4.x, w4.x, acc[0][0]);
      acc[0][1] = fmaf(e4.x, w4.y, acc[0][1]);
      acc[0][2] = fmaf(e4.x, w4.z, acc[0][2]);
      acc[0][3] = fmaf(e4.x, w4.w, acc[0][3]);
      acc[1][0] = fmaf(e4.y, w4.x, acc[1][0]);
      acc[1][1] = fmaf(e4.y, w4.y, acc[1][1]);
      acc[1][2] = fmaf(e4.y, w4.z, acc[1][2]);
      acc[1][3] = fmaf(e4.y, w4.w, acc[1][3]);
      acc[2][0] = fmaf(e4.z, w4.x, acc[2][0]);
      acc[2][1] = fmaf(e4.z, w4.y, acc[2][1]);
      acc[2][2] = fmaf(e4.z, w4.z, acc[2][2]);
      acc[2][3] = fmaf(e4.z, w4.w, acc[2][3]);
      acc[3][0] = fmaf(e4.w, w4.x, acc[3][0]);
      acc[3][1] = fmaf(e4.w, w4.y, acc[3][1]);
      acc[3][2] = fmaf(e4.w, w4.z, acc[3][2]);
      acc[3][3] = fmaf(e4.w, w4.w, acc[3][3]);
    }
  }
  if (tx == 0) {
    Dl[uy * 4 + 0] = d0; Dl[uy * 4 + 1] = d1;
    Dl[uy * 4 + 2] = d2; Dl[uy * 4 + 3] = d3;
  }
  __syncthreads();
#pragma unroll
  for (int j = 0; j < 4; ++j) {
    int u = uy * 4 + j;
    float dinv = 1.0f / Dl[u];
    float4 o;
    o.x = fmaf(acc[j][0], dinv, bp[tx * 4 + 0]);
    o.y = fmaf(acc[j][1], dinv, bp[tx * 4 + 1]);
    o.z = fmaf(acc[j][2], dinv, bp[tx * 4 + 2]);
    o.w = fmaf(acc[j][3], dinv, bp[tx * 4 + 3]);
    *(float4*)&out[(((size_t)(b * TT + t) * UU + u) * NV) + tx * 4] = o;
  }
}

extern "C" void kernel_launch(void* const* d_in, const int* in_sizes, int n_in,
                              void* d_out, int out_size, void* d_ws, size_t ws_size,
                              hipStream_t stream) {
  (void)in_sizes; (void)n_in; (void)out_size; (void)ws_size;
  const float* encoder_inp   = (const float*)d_in[0];
  const int*   pred_inp      = (const int*)d_in[1];
  const float* encoder_state = (const float*)d_in[2];
  const float* enc_W0 = (const float*)d_in[3];
  const float* enc_U0 = (const float*)d_in[4];
  const float* enc_b0 = (const float*)d_in[5];
  const float* enc_W1 = (const float*)d_in[6];
  const float* enc_U1 = (const float*)d_in[7];
  const float* enc_b1 = (const float*)d_in[8];
  const float* embed   = (const float*)d_in[9];
  const float* pred_W0 = (const float*)d_in[10];
  const float* pred_U0 = (const float*)d_in[11];
  const float* pred_b0 = (const float*)d_in[12];
  const float* pred_W1 = (const float*)d_in[13];
  const float* pred_U1 = (const float*)d_in[14];
  const float* pred_b1 = (const float*)d_in[15];
  const float* Wj = (const float*)d_in[16];
  const float* bj = (const float*)d_in[17];
  const float* Ws = (const float*)d_in[18];
  const float* bs = (const float*)d_in[19];
  const float* Wp = (const float*)d_in[20];
  const float* bp = (const float*)d_in[21];
  float* outp = (float*)d_out;

  char* wsb = (char*)d_ws;
  size_t off = 0;
  auto alloc = [&](size_t bytes) -> void* {
    void* p = (void*)(wsb + off);
    off += (bytes + 255) & ~(size_t)255;
    return p;
  };
  float*    Ut_e0 = (float*)alloc((size_t)G4 * HD * 4);
  float*    Ut_e1 = (float*)alloc((size_t)G4 * HD * 4);
  ushort_t* Ut_p0 = (ushort_t*)alloc((size_t)G4 * HD * 2);
  ushort_t* Ut_p1 = (ushort_t*)alloc((size_t)G4 * HD * 2);
  float* xg_e0 = (float*)alloc((size_t)NB * TT * G4 * 4);
  float* ptab  = (float*)alloc((size_t)NV * G4 * 4);
  float* xg_e1 = (float*)alloc((size_t)NB * TT * G4 * 4);
  float* xg_p1 = (float*)alloc((size_t)NB * UU * G4 * 4);
  float* h0s  = (float*)alloc((size_t)NB * TT * HD * 4);
  float* hp0s = (float*)alloc((size_t)NB * UU * HD * 4);
  float* h1s  = (float*)alloc((size_t)NB * TT * HD * 4);
  float* hp1s = (float*)alloc((size_t)NB * UU * HD * 4);
  float* xjb = (float*)alloc((size_t)NB * TT * JD * 4);
  float* pjb = (float*)alloc((size_t)NB * UU * JD * 4);
  float* xsb = (float*)alloc((size_t)NB * TT * SMAXD * 4);
  float* psb = (float*)alloc((size_t)NB * UU * SMAXD * 4);
  float* csb = (float*)alloc((size_t)SMAXD * 4);
  float* chunks = (float*)alloc((size_t)4 * 2 * 128 * CHK * 4);  // 4 groups x [2][128][CHK]

  float* chk_e0 = chunks + 0 * (2 * 128 * CHK);
  float* chk_p0 = chunks + 1 * (2 * 128 * CHK);
  float* chk_e1 = chunks + 2 * (2 * 128 * CHK);
  float* chk_p1 = chunks + 3 * (2 * 128 * CHK);

  // zero all chunks (tags=0, pred initial h=0), then fill enc initial h (parity 0)
  hipMemsetAsync(chunks, 0, (size_t)4 * 2 * 128 * CHK * 4, stream);
  init_chunks<<<16, 256, 0, stream>>>(encoder_state, chk_e0, chk_e1);

  dim3 tb(32, 8);
  transpose_f32 <<<dim3(G4 / 32, HD / 32), tb, 0, stream>>>(enc_U0, Ut_e0, HD, G4);
  transpose_f32 <<<dim3(G4 / 32, HD / 32), tb, 0, stream>>>(enc_U1, Ut_e1, HD, G4);
  transpose_bf16<<<dim3(G4 / 32, HD / 32), tb, 0, stream>>>(pred_U0, Ut_p0, HD, G4);
  transpose_bf16<<<dim3(G4 / 32, HD / 32), tb, 0, stream>>>(pred_U1, Ut_p1, HD, G4);

  inproj_kernel<<<NB * TT, 256, 0, stream>>>(encoder_inp, enc_W0, enc_b0, xg_e0, NFEAT);
  inproj_kernel<<<NV, 256, 0, stream>>>(embed, pred_W0, pred_b0, ptab, 64);

  // phase 1: enc0 (blocks 0..127) || pred0 (blocks 128..255)
  lstm_kernel<<<256, 256, 0, stream>>>(
      xg_e0, TT, Ut_e0, encoder_state + NB * HD, h0s, chk_e0, nullptr,
      ptab, UU, pred_inp, Ut_p0, hp0s, chk_p0);

  // layer-1 input projections (batched)
  gemm_kernel<<<dim3(G4 / 64, (NB * TT) / 64), 256, 0, stream>>>(h0s, enc_W1, enc_b1, xg_e1, NB * TT, G4, HD);
  gemm_kernel<<<dim3(G4 / 64, (NB * UU) / 64), 256, 0, stream>>>(hp0s, pred_W1, pred_b1, xg_p1, NB * UU, G4, HD);

  // phase 2: enc1 || pred1 ; enc1 writes final state to d_out tail
  lstm_kernel<<<256, 256, 0, stream>>>(
      xg_e1, TT, Ut_e1, encoder_state + NB * HD, h1s, chk_e1,
      outp + (size_t)NB * TT * UU * NV,
      xg_p1, UU, nullptr, Ut_p1, hp1s, chk_p1);

  // factored joint: xs = (x@Wj)@Ws ; ps = (p@Wj)@Ws ; cs = bj@Ws + bs
  gemm_kernel<<<dim3(JD / 64, (NB * TT) / 64), 256, 0, stream>>>(h1s, Wj, nullptr, xjb, NB * TT, JD, HD);
  gemm_kernel<<<dim3(JD / 64, (NB * UU) / 64), 256, 0, stream>>>(hp1s, Wj, nullptr, pjb, NB * UU, JD, HD);
  gemm_kernel<<<dim3(SMAXD / 64, (NB * TT) / 64), 256, 0, stream>>>(xjb, Ws, nullptr, xsb, NB * TT, SMAXD, JD);
  gemm_kernel<<<dim3(SMAXD / 64, (NB * UU) / 64), 256, 0, stream>>>(pjb, Ws, nullptr, psb, NB * UU, SMAXD, JD);
  cs_kernel<<<SMAXD / 256, 256, 0, stream>>>(bj, Ws, bs, csb);

  final_kernel<<<NB * TT, 256, 0, stream>>>(xsb, psb, csb, Wp, bp, outp);
}